// Round 1
// 2971.147 us; speedup vs baseline: 1.6270x; 1.6270x over previous
//
#include <hip/hip_runtime.h>
#include <hip/hip_bf16.h>

typedef __hip_bfloat16 bf16;
typedef __attribute__((ext_vector_type(8))) short bf16x8;   // 8 bf16 = 4 VGPRs (MFMA A/B frag)
typedef __attribute__((ext_vector_type(4))) float f32x4;    // MFMA C/D frag

#define NT   37824   // total tokens = 192*197
#define EDIM 768
#define N3   2304
#define TP   197     // tokens per frame
#define NB   16
#define NF   12
#define NH   12
#define HD   64
#define SCALE 0.125f
#define KALL 2364    // 12*197

__device__ __forceinline__ float bits2f(unsigned short u) {
    unsigned int v = ((unsigned int)u) << 16;
    return __uint_as_float(v);
}
__device__ __forceinline__ float b2f(bf16 v) { return __bfloat162float(v); }

__device__ __forceinline__ float4 load4(const float* p) { return *reinterpret_cast<const float4*>(p); }
__device__ __forceinline__ float4 load4(const bf16* p) {
    ushort4 u = *reinterpret_cast<const ushort4*>(p);
    return make_float4(bits2f(u.x), bits2f(u.y), bits2f(u.z), bits2f(u.w));
}
__device__ __forceinline__ void storeC(float* p, float v) { *p = v; }
__device__ __forceinline__ void storeC(bf16* p, float v) { *p = __float2bfloat16(v); }

// ---------------- K1: mid = x @ lora_a^T  (NT x 8), fp32 in ----------------
__global__ __launch_bounds__(256) void lora_mid_kernel(const float* __restrict__ x,
        const float* __restrict__ la, float* __restrict__ mid) {
    int t = blockIdx.x * 4 + (threadIdx.x >> 6);
    int lane = threadIdx.x & 63;
    if (t >= NT) return;
    float acc[8];
#pragma unroll
    for (int r = 0; r < 8; r++) acc[r] = 0.f;
    const float* xr = x + (size_t)t * EDIM;
    for (int e = lane; e < EDIM; e += 64) {
        float xv = xr[e];
#pragma unroll
        for (int r = 0; r < 8; r++) acc[r] += xv * la[r * EDIM + e];
    }
#pragma unroll
    for (int r = 0; r < 8; r++) {
        float v = acc[r];
#pragma unroll
        for (int off = 32; off >= 1; off >>= 1) v += __shfl_xor(v, off, 64);
        if (lane == 0) mid[(size_t)t * 8 + r] = v;
    }
}

// ---------------- Tiled SGEMM: C = A @ W^T + bias (+ mid @ lora_b^T) ----------------
// A: MxK (AT = float or bf16), W: NxK fp32, C: MxN (OT). 128x128 tile, TK=16, 8x8/thread.
template <typename AT, typename OT, bool LORA>
__global__ __launch_bounds__(256) void gemm_kernel(const AT* __restrict__ A,
        const float* __restrict__ W, const float* __restrict__ bias,
        const float* __restrict__ mid, const float* __restrict__ lb,
        OT* __restrict__ C, int M, int N, int K) {
    __shared__ float As[16][128];
    __shared__ float Bs[16][128];
    const int tid = threadIdx.x;
    const int tx = tid & 15, ty = tid >> 4;
    const int m0 = blockIdx.y * 128, n0 = blockIdx.x * 128;
    float acc[8][8];
#pragma unroll
    for (int i = 0; i < 8; i++) {
#pragma unroll
        for (int j = 0; j < 8; j++) acc[i][j] = 0.f;
    }
    const int rr = tid >> 2;
    const int c4 = (tid & 3) * 4;
    for (int k0 = 0; k0 < K; k0 += 16) {
#pragma unroll
        for (int ph = 0; ph < 2; ph++) {
            int r = rr + ph * 64;
            int m = m0 + r;
            float4 av = make_float4(0.f, 0.f, 0.f, 0.f);
            if (m < M) av = load4(A + (size_t)m * K + k0 + c4);
            As[c4 + 0][r] = av.x; As[c4 + 1][r] = av.y; As[c4 + 2][r] = av.z; As[c4 + 3][r] = av.w;
            int n = n0 + r;  // N is always a multiple of 128 here
            float4 bv = load4(W + (size_t)n * K + k0 + c4);
            Bs[c4 + 0][r] = bv.x; Bs[c4 + 1][r] = bv.y; Bs[c4 + 2][r] = bv.z; Bs[c4 + 3][r] = bv.w;
        }
        __syncthreads();
#pragma unroll
        for (int k = 0; k < 16; k++) {
            float a[8], b[8];
            *(float4*)&a[0] = *(const float4*)&As[k][ty * 8];
            *(float4*)&a[4] = *(const float4*)&As[k][ty * 8 + 4];
            *(float4*)&b[0] = *(const float4*)&Bs[k][tx * 8];
            *(float4*)&b[4] = *(const float4*)&Bs[k][tx * 8 + 4];
#pragma unroll
            for (int i = 0; i < 8; i++) {
#pragma unroll
                for (int j = 0; j < 8; j++) acc[i][j] += a[i] * b[j];
            }
        }
        __syncthreads();
    }
#pragma unroll
    for (int i = 0; i < 8; i++) {
        int m = m0 + ty * 8 + i;
        if (m < M) {
            float mrow[8];
            if constexpr (LORA) {
                float4 u = *(const float4*)&mid[(size_t)m * 8];
                float4 v = *(const float4*)&mid[(size_t)m * 8 + 4];
                mrow[0] = u.x; mrow[1] = u.y; mrow[2] = u.z; mrow[3] = u.w;
                mrow[4] = v.x; mrow[5] = v.y; mrow[6] = v.z; mrow[7] = v.w;
            }
#pragma unroll
            for (int j = 0; j < 8; j++) {
                int n = n0 + tx * 8 + j;
                float v = acc[i][j] + bias[n];
                if constexpr (LORA) {
                    const float4 l0 = *reinterpret_cast<const float4*>(lb + (size_t)n * 8);
                    const float4 l1 = *reinterpret_cast<const float4*>(lb + (size_t)n * 8 + 4);
                    v += mrow[0] * l0.x + mrow[1] * l0.y + mrow[2] * l0.z + mrow[3] * l0.w
                       + mrow[4] * l1.x + mrow[5] * l1.y + mrow[6] * l1.z + mrow[7] * l1.w;
                }
                storeC(C + (size_t)m * N + n, v);
            }
        }
    }
}

// ---------------- Fused per-frame attention, MFMA version ----------------
// One block per (bb, h). 4 waves; wave w owns 16-row Q-tiles {w, w+4, w+8, (12)}.
// mfma_f32_16x16x32_bf16 layouts (learn_hip m89/m92):
//   A: row = lane%16, k = (lane>>4)*8 + e   (8 contiguous bf16 -> one b128 read)
//   B: col = lane%16, k = (lane>>4)*8 + e
//   C: col = lane&15, row = (lane>>4)*4 + reg
// K in LDS [208][64] row-major, V in LDS TRANSPOSED [64][208] (so PV's B-frag is
// contiguous in k). Both XOR-swizzled byte ^= ((row&7)<<4) to kill the 16-way
// stride-128B bank conflict (Guideline 4). P round-trips through a per-wave
// swizzled LDS buffer [16][208] (C-layout -> A-layout transpose).
// Total LDS = 3*26624 = 79872 B -> exactly 2 blocks/CU.
__global__ __launch_bounds__(256) void attn_kernel(const bf16* __restrict__ qkv,
        bf16* __restrict__ ao) {
    __shared__ bf16 Ks[208 * 64];      // [row][64]
    __shared__ bf16 Vt[64 * 208];      // [d][kk]
    __shared__ bf16 Ps[4][16 * 208];   // per-wave [q][kk]
    const int bb = blockIdx.x / NH;
    const int h = blockIdx.x % NH;
    const bf16* base = qkv + (size_t)bb * TP * N3;
    const int tid = threadIdx.x;
    const int w = tid >> 6, lane = tid & 63;
    const int lr = lane & 15, lg = lane >> 4;

    // ---- stage K rows 0..207 (zero-fill >=197), swizzled ----
    for (int idx = tid; idx < 208 * 16; idx += 256) {
        int row = idx >> 4, d4 = (idx & 15) * 4;
        ushort4 v = make_ushort4(0, 0, 0, 0);
        if (row < TP)
            v = *(const ushort4*)(base + (size_t)row * N3 + EDIM + h * 64 + d4);
        *(ushort4*)((char*)Ks + ((row * 128 + d4 * 2) ^ ((row & 7) << 4))) = v;
    }
    // ---- stage V transposed: Vt[d][kk] (zero-fill kk>=197), swizzled ----
    for (int g = w; g < 52; g += 4) {
        int kk0 = g * 4;
        int d = lane;
        const bf16* vb = base + (size_t)kk0 * N3 + 2 * EDIM + h * 64 + d;
        unsigned short t0 = 0, t1 = 0, t2 = 0, t3 = 0;
        if (kk0 + 0 < TP) t0 = *(const unsigned short*)(vb);
        if (kk0 + 1 < TP) t1 = *(const unsigned short*)(vb + N3);
        if (kk0 + 2 < TP) t2 = *(const unsigned short*)(vb + 2 * N3);
        if (kk0 + 3 < TP) t3 = *(const unsigned short*)(vb + 3 * N3);
        ushort4 v; v.x = t0; v.y = t1; v.z = t2; v.w = t3;
        *(ushort4*)((char*)Vt + ((d * 416 + kk0 * 2) ^ ((d & 7) << 4))) = v;
    }
    __syncthreads();   // only barrier in the kernel; waves independent after this

    bf16* Pw = &Ps[w][0];

    for (int qt = w; qt < 13; qt += 4) {
        // ---- Q A-frags straight from global (bf16, 16B aligned) ----
        int q = qt * 16 + lr; if (q > TP - 1) q = TP - 1;   // clamp; dup rows discarded
        const bf16* qp = base + (size_t)q * N3 + h * 64 + lg * 8;
        bf16x8 qa0 = *(const bf16x8*)qp;
        bf16x8 qa1 = *(const bf16x8*)(qp + 32);

        // ---- S = (Q @ K^T) * SCALE : 13 col-frags of 16 keys ----
        f32x4 sf[13];
#pragma unroll
        for (int f = 0; f < 13; f++) {
            int row = f * 16 + lr;                 // key index = B col
            int swz = (row & 7) << 4;
            bf16x8 kb0 = *(const bf16x8*)((const char*)Ks + ((row * 128 + lg * 16) ^ swz));
            bf16x8 kb1 = *(const bf16x8*)((const char*)Ks + ((row * 128 + 64 + lg * 16) ^ swz));
            f32x4 c = {0.f, 0.f, 0.f, 0.f};
            c = __builtin_amdgcn_mfma_f32_16x16x32_bf16(qa0, kb0, c, 0, 0, 0);
            c = __builtin_amdgcn_mfma_f32_16x16x32_bf16(qa1, kb1, c, 0, 0, 0);
            sf[f] = c;
        }

        // ---- softmax over 197 keys (rows live in 16-lane groups) ----
        float mx[4] = {-1e30f, -1e30f, -1e30f, -1e30f};
#pragma unroll
        for (int f = 0; f < 13; f++) {
#pragma unroll
            for (int r = 0; r < 4; r++) {
                float s = sf[f][r] * SCALE;
                if (f == 12 && lr >= 5) s = -1e30f;   // keys 197..207 invalid
                sf[f][r] = s;
                mx[r] = fmaxf(mx[r], s);
            }
        }
#pragma unroll
        for (int off = 8; off >= 1; off >>= 1) {
#pragma unroll
            for (int r = 0; r < 4; r++) mx[r] = fmaxf(mx[r], __shfl_xor(mx[r], off, 64));
        }
        float lsum[4] = {0.f, 0.f, 0.f, 0.f};
#pragma unroll
        for (int f = 0; f < 13; f++) {
#pragma unroll
            for (int r = 0; r < 4; r++) {
                float e = __expf(sf[f][r] - mx[r]);   // masked -> exp(-huge) = 0
                sf[f][r] = e;
                lsum[r] += e;
            }
        }
#pragma unroll
        for (int off = 8; off >= 1; off >>= 1) {
#pragma unroll
            for (int r = 0; r < 4; r++) lsum[r] += __shfl_xor(lsum[r], off, 64);
        }
        float inv[4];
#pragma unroll
        for (int r = 0; r < 4; r++) inv[r] = 1.f / lsum[r];

        // ---- P (C-layout) -> per-wave LDS (A-layout source), bf16, swizzled ----
#pragma unroll
        for (int f = 0; f < 13; f++) {
#pragma unroll
            for (int r = 0; r < 4; r++) {
                int row = lg * 4 + r;
                int col = f * 16 + lr;
                *(bf16*)((char*)Pw + ((row * 416 + col * 2) ^ ((row & 7) << 4))) =
                    __float2bfloat16(sf[f][r]);
            }
        }
        // intra-wave ds_write -> ds_read dependence: compiler inserts lgkmcnt wait

        // ---- O = P @ V : 7 K-steps of 32 keys, 4 d-col frags ----
        f32x4 of[4];
#pragma unroll
        for (int dt = 0; dt < 4; dt++) of[dt] = (f32x4){0.f, 0.f, 0.f, 0.f};
#pragma unroll
        for (int ks = 0; ks < 7; ks++) {
            int k0 = ks * 32 + lg * 8;
            bool ok = (k0 < 208);                  // ks==6, lg>=2 -> zero frag
            bf16x8 pa = {0, 0, 0, 0, 0, 0, 0, 0};
            if (ok)
                pa = *(const bf16x8*)((const char*)Pw + ((lr * 416 + k0 * 2) ^ ((lr & 7) << 4)));
#pragma unroll
            for (int dt = 0; dt < 4; dt++) {
                bf16x8 vb = {0, 0, 0, 0, 0, 0, 0, 0};
                if (ok) {
                    int d = dt * 16 + lr;
                    vb = *(const bf16x8*)((const char*)Vt + ((d * 416 + k0 * 2) ^ ((d & 7) << 4)));
                }
                of[dt] = __builtin_amdgcn_mfma_f32_16x16x32_bf16(pa, vb, of[dt], 0, 0, 0);
            }
        }

        // ---- epilogue: scale by 1/l, store bf16 ----
#pragma unroll
        for (int dt = 0; dt < 4; dt++) {
#pragma unroll
            for (int r = 0; r < 4; r++) {
                int qq = qt * 16 + lg * 4 + r;
                if (qq < TP)
                    ao[((size_t)bb * TP + qq) * EDIM + h * 64 + dt * 16 + lr] =
                        __float2bfloat16(of[dt][r] * inv[r]);
            }
        }
    }
}

// ---------------- Fused cross-frame CLS attention (flash-style online softmax) ----------
__global__ __launch_bounds__(256) void xattn_kernel(const bf16* __restrict__ qkv,
        float* __restrict__ x1p) {
    __shared__ float q1[NF][64];
    __shared__ bf16 Ks[128][64];
    __shared__ bf16 Vs[128][64];
    __shared__ float sc[NF][128];
    __shared__ float Oacc[NF][64];
    __shared__ float mrow[NF], lrow[NF], arow[NF];
    const int b = blockIdx.x / NH, h = blockIdx.x % NH;
    const int tid = threadIdx.x;
    for (int idx = tid; idx < NF * 64; idx += 256) {
        int f = idx >> 6, d = idx & 63;
        q1[f][d] = b2f(qkv[(size_t)((b * NF + f) * TP) * N3 + h * 64 + d]);
        Oacc[f][d] = 0.f;
    }
    if (tid < NF) { mrow[tid] = -1e30f; lrow[tid] = 0.f; }
    __syncthreads();
    const int w = tid >> 6, lane = tid & 63;
    for (int kk0 = 0; kk0 < KALL; kk0 += 128) {
        for (int idx = tid; idx < 128 * 16; idx += 256) {
            int r = idx >> 4, d4 = (idx & 15) * 4;
            int kk = kk0 + r;
            if (kk < KALL) {
                int f = kk / TP, pp = kk - f * TP;
                const bf16* src = qkv + (size_t)((b * NF + f) * TP + pp) * N3 + h * 64 + d4;
                *(ushort4*)&Ks[r][d4] = *(const ushort4*)(src + 768);
                *(ushort4*)&Vs[r][d4] = *(const ushort4*)(src + 1536);
            } else {
                ushort4 z; z.x = z.y = z.z = z.w = 0;
                *(ushort4*)&Ks[r][d4] = z;
                *(ushort4*)&Vs[r][d4] = z;
            }
        }
        __syncthreads();
        for (int idx = tid; idx < NF * 128; idx += 256) {
            int f = idx >> 7, r = idx & 127;
            float s = -1e30f;
            if (kk0 + r < KALL) {
                const bf16* kr = &Ks[r][0];
                float a = 0.f;
#pragma unroll
                for (int d2 = 0; d2 < 32; d2++) {
                    unsigned int u = *reinterpret_cast<const unsigned int*>(kr + 2 * d2);
                    a += q1[f][2 * d2] * __uint_as_float(u << 16);
                    a += q1[f][2 * d2 + 1] * __uint_as_float(u & 0xffff0000u);
                }
                s = a * SCALE;
            }
            sc[f][r] = s;
        }
        __syncthreads();
        for (int qi = 0; qi < 3; qi++) {
            int f = qi * 4 + w;
            float s0 = sc[f][lane], s1v = sc[f][lane + 64];
            float mx = fmaxf(s0, s1v);
#pragma unroll
            for (int off = 32; off >= 1; off >>= 1) mx = fmaxf(mx, __shfl_xor(mx, off, 64));
            float mold = mrow[f];
            float mnew = fmaxf(mold, mx);
            float e0 = __expf(s0 - mnew), e1 = __expf(s1v - mnew);
            float ls = e0 + e1;
#pragma unroll
            for (int off = 32; off >= 1; off >>= 1) ls += __shfl_xor(ls, off, 64);
            sc[f][lane] = e0; sc[f][lane + 64] = e1;
            if (lane == 0) {
                float alpha = __expf(mold - mnew);
                arow[f] = alpha;
                lrow[f] = lrow[f] * alpha + ls;
                mrow[f] = mnew;
            }
        }
        __syncthreads();
        for (int idx = tid; idx < NF * 64; idx += 256) {
            int f = idx >> 6, d = idx & 63;
            float o = Oacc[f][d] * arow[f];
#pragma unroll 4
            for (int r = 0; r < 128; r++)
                o += sc[f][r] * b2f(Vs[r][d]);
            Oacc[f][d] = o;
        }
        __syncthreads();
    }
    for (int idx = tid; idx < NF * 64; idx += 256) {
        int f = idx >> 6, d = idx & 63;
        x1p[(size_t)(b * NF + f) * EDIM + h * 64 + d] = Oacc[f][d] / lrow[f];
    }
}

// ---------------- CLS fixup: out[:,:,0,:] = MLP(out[:,:,0,:]) + x1p @ Wout^T + ob --------
__global__ __launch_bounds__(256) void cls_kernel(float* __restrict__ out,
        const float* __restrict__ x1p, const float* __restrict__ Wout, const float* __restrict__ ob,
        const float* __restrict__ dw, const float* __restrict__ db,
        const float* __restrict__ uw, const float* __restrict__ ub) {
    __shared__ float x0s[EDIM], x1s[EDIM], gs[8];
    const int bfi = blockIdx.x;
    float* row = out + (size_t)bfi * TP * EDIM;  // p = 0 row
    const int tid = threadIdx.x;
    for (int i = tid; i < EDIM; i += 256) {
        x0s[i] = row[i];
        x1s[i] = x1p[(size_t)bfi * EDIM + i];
    }
    __syncthreads();
    {
        int r = tid >> 5, sl = tid & 31;
        float pr = 0.f;
        for (int e = sl; e < EDIM; e += 32) pr += x0s[e] * dw[r * EDIM + e];
#pragma unroll
        for (int off = 16; off >= 1; off >>= 1) pr += __shfl_xor(pr, off, 64);
        if (sl == 0) gs[r] = pr + db[r];
    }
    __syncthreads();
    float act[8];
#pragma unroll
    for (int r = 0; r < 8; r++) { float g = gs[r]; act[r] = g / (1.f + __expf(-1.702f * g)); }
    for (int j = tid; j < EDIM; j += 256) {
        float y = ub[j] + ob[j];
        const float4 u0 = *reinterpret_cast<const float4*>(uw + (size_t)j * 8);
        const float4 u1 = *reinterpret_cast<const float4*>(uw + (size_t)j * 8 + 4);
        y += act[0] * u0.x + act[1] * u0.y + act[2] * u0.z + act[3] * u0.w
           + act[4] * u1.x + act[5] * u1.y + act[6] * u1.z + act[7] * u1.w;
        const float* wr = Wout + (size_t)j * EDIM;
        float s = 0.f;
        for (int e = 0; e < EDIM; e += 4) {
            float4 wv = *reinterpret_cast<const float4*>(wr + e);
            s += x1s[e] * wv.x + x1s[e + 1] * wv.y + x1s[e + 2] * wv.z + x1s[e + 3] * wv.w;
        }
        y += s;
        row[j] = y;
    }
}

extern "C" void kernel_launch(void* const* d_in, const int* in_sizes, int n_in,
                              void* d_out, int out_size, void* d_ws, size_t ws_size,
                              hipStream_t stream) {
    (void)in_sizes; (void)n_in; (void)out_size; (void)ws_size;
    const float* x   = (const float*)d_in[0];
    const float* ipw = (const float*)d_in[1];
    const float* ipb = (const float*)d_in[2];
    const float* opw = (const float*)d_in[3];
    const float* opb = (const float*)d_in[4];
    const float* la  = (const float*)d_in[5];
    const float* lb  = (const float*)d_in[6];
    const float* dw  = (const float*)d_in[7];
    const float* db  = (const float*)d_in[8];
    const float* uw  = (const float*)d_in[9];
    const float* ub  = (const float*)d_in[10];
    float* out = (float*)d_out;   // fp32 output per reference dtype

    // workspace: qkv bf16 174.3MB + ao bf16 58.1MB + mid fp32 1.2MB + x1p 0.6MB = 234.2MB
    char* wsb = (char*)d_ws;
    bf16* qkv = (bf16*)wsb;                       wsb += (size_t)NT * N3 * sizeof(bf16);
    bf16* ao  = (bf16*)wsb;                       wsb += (size_t)NT * EDIM * sizeof(bf16);
    float* mid = (float*)wsb;                     wsb += (size_t)NT * 8 * sizeof(float);
    float* x1p = (float*)wsb;                     wsb += (size_t)NB * NF * EDIM * sizeof(float);

    lora_mid_kernel<<<NT / 4, 256, 0, stream>>>(x, la, mid);
    gemm_kernel<float, bf16, true><<<dim3(N3 / 128, (NT + 127) / 128), 256, 0, stream>>>(
        x, ipw, ipb, mid, lb, qkv, NT, N3, EDIM);
    attn_kernel<<<192 * NH, 256, 0, stream>>>(qkv, ao);
    xattn_kernel<<<NB * NH, 256, 0, stream>>>(qkv, x1p);
    gemm_kernel<bf16, float, false><<<dim3(EDIM / 128, (NT + 127) / 128), 256, 0, stream>>>(
        ao, opw, opb, nullptr, nullptr, out, NT, EDIM, EDIM);
    cls_kernel<<<NB * NF, 256, 0, stream>>>(out, x1p, opw, opb, dw, db, uw, ub);
}

// Round 2
// 2516.620 us; speedup vs baseline: 1.9208x; 1.1806x over previous
//
#include <hip/hip_runtime.h>
#include <hip/hip_bf16.h>

typedef __hip_bfloat16 bf16;
typedef __attribute__((ext_vector_type(8))) short bf16x8;   // 8 bf16 = 4 VGPRs (MFMA A/B frag)
typedef __attribute__((ext_vector_type(4))) float f32x4;    // MFMA C/D frag

#define NT   37824   // total tokens = 192*197
#define MPAD 37888   // 296*128 (padded rows for 128-tile GEMM)
#define EDIM 768
#define N3   2304
#define TP   197     // tokens per frame
#define NB   16
#define NF   12
#define NH   12
#define HD   64
#define SCALE 0.125f
#define KALL 2364    // 12*197

__device__ __forceinline__ float bits2f(unsigned short u) {
    unsigned int v = ((unsigned int)u) << 16;
    return __uint_as_float(v);
}
__device__ __forceinline__ float b2f(bf16 v) { return __bfloat162float(v); }

__device__ __forceinline__ unsigned short bhi(float x) {
    union { bf16 b; unsigned short u; } cv; cv.b = __float2bfloat16(x); return cv.u;
}
__device__ __forceinline__ unsigned short blo(float x, unsigned short h) {
    float hf = __uint_as_float(((unsigned int)h) << 16);
    union { bf16 b; unsigned short u; } cv; cv.b = __float2bfloat16(x - hf); return cv.u;
}

__device__ __forceinline__ void storeC(float* p, float v) { *p = v; }
__device__ __forceinline__ void storeC(bf16* p, float v) { *p = __float2bfloat16(v); }

// async global->LDS, 16B per lane; lds dest = wave-uniform base + lane*16
__device__ __forceinline__ void gload_lds16(const bf16* g, bf16* l) {
    __builtin_amdgcn_global_load_lds(
        (const __attribute__((address_space(1))) void*)g,
        (__attribute__((address_space(3))) void*)l,
        16, 0, 0);
}

// ---------------- K1: mid = x @ lora_a^T  (NT x 8), fp32 in ----------------
__global__ __launch_bounds__(256) void lora_mid_kernel(const float* __restrict__ x,
        const float* __restrict__ la, float* __restrict__ mid) {
    int t = blockIdx.x * 4 + (threadIdx.x >> 6);
    int lane = threadIdx.x & 63;
    if (t >= NT) return;
    float acc[8];
#pragma unroll
    for (int r = 0; r < 8; r++) acc[r] = 0.f;
    const float* xr = x + (size_t)t * EDIM;
    for (int e = lane; e < EDIM; e += 64) {
        float xv = xr[e];
#pragma unroll
        for (int r = 0; r < 8; r++) acc[r] += xv * la[r * EDIM + e];
    }
#pragma unroll
    for (int r = 0; r < 8; r++) {
        float v = acc[r];
#pragma unroll
        for (int off = 32; off >= 1; off >>= 1) v += __shfl_xor(v, off, 64);
        if (lane == 0) mid[(size_t)t * 8 + r] = v;
    }
}

// ---------------- split fp32 W (rows x 768) -> bf16 [W_hi | W_lo] (rows x 1536) ----------
__global__ __launch_bounds__(256) void split_w_kernel(const float* __restrict__ w,
        bf16* __restrict__ o, int rows) {
    int idx = blockIdx.x * 256 + threadIdx.x;
    int total = rows * 192;                        // 768/4 float4-chunks per row
    if (idx >= total) return;
    int r = idx / 192, c = (idx - r * 192) * 4;
    float4 v = *reinterpret_cast<const float4*>(w + (size_t)r * 768 + c);
    ushort4 hi, lo;
    hi.x = bhi(v.x); hi.y = bhi(v.y); hi.z = bhi(v.z); hi.w = bhi(v.w);
    lo.x = blo(v.x, hi.x); lo.y = blo(v.y, hi.y); lo.z = blo(v.z, hi.z); lo.w = blo(v.w, hi.w);
    *(ushort4*)(o + (size_t)r * 1536 + c) = hi;
    *(ushort4*)(o + (size_t)r * 1536 + 768 + c) = lo;
}

// ---------------- MFMA GEMM: C = A @ Wsplit^T + bias (+ mid @ lora_b^T) ----------------
// Virtual-K decomposition (fp32 accuracy from bf16 MFMA):
//   A col  = k % 768   (AT=float: convert to HI for k<1536, LO for k>=1536;
//                       AT=bf16 : plain duplication, KV=1536)
//   W col  = k % 1536  (W is pre-split bf16 [W_hi | W_lo], row stride 1536)
// => KV=2304: x_hi@Whi + x_hi@Wlo + x_lo@Whi ; KV=1536: ao@Whi + ao@Wlo.
// 128x128 tile, BK=64, 4 waves (2x2 of 64x64), mfma_f32_16x16x32_bf16.
// LDS tiles [128 rows][64 bf16] XOR-swizzled byte^=((row&7)<<4): the 16-lane
// column-slice ds_read_b128 hits 8 distinct 16B slots per 8 lanes -> conflict-free.
// A reg-staged (conversion); B via global_load_lds(16) with pre-swizzled source.
template <typename AT, typename OT, bool LORA>
__global__ __launch_bounds__(256) void mfma_gemm_kernel(const AT* __restrict__ A,
        const bf16* __restrict__ W, const float* __restrict__ bias,
        const float* __restrict__ mid, const float* __restrict__ lb,
        OT* __restrict__ C, int M, int N, int KV) {
    __shared__ bf16 As[128 * 64];
    __shared__ bf16 Bs[128 * 64];
    const int tid = threadIdx.x;
    const int w = tid >> 6, lane = tid & 63;
    const int lr = lane & 15, lg = lane >> 4;
    const int wr = w >> 1, wc = w & 1;

    // bijective XCD-chunk swizzle (nwg % 8 == 0 for both launches)
    const int gx = gridDim.x;
    const int nwg = gx * gridDim.y;
    const int flat = blockIdx.y * gx + blockIdx.x;
    const int cpx = nwg >> 3;
    const int lid = (flat & 7) * cpx + (flat >> 3);
    const int m0 = (lid / gx) * 128, n0 = (lid % gx) * 128;

    f32x4 acc[4][4];
#pragma unroll
    for (int i = 0; i < 4; i++)
#pragma unroll
        for (int j = 0; j < 4; j++) acc[i][j] = (f32x4){0.f, 0.f, 0.f, 0.f};

    // B-staging source swizzle (rule #21: linear LDS dest, inverse-swizzled source)
    const int brs = lane >> 3;                 // row within 8-row wave chunk (= row&7)
    const int bcsw = ((lane & 7) ^ brs) << 3;  // swizzled col offset, elems

    for (int k0 = 0; k0 < KV; k0 += 64) {
        const int aCol = k0 % 768;
        const int wCol = k0 % 1536;
        __syncthreads();
        // ---- stage A (reg-staged, swizzled ds_write) ----
        if constexpr (sizeof(AT) == 4) {       // fp32 x -> bf16 hi/lo on the fly
            const bool low = (k0 >= 1536);
#pragma unroll
            for (int i = 0; i < 8; i++) {
                int c = tid + i * 256;          // 2048 float4-chunks
                int row = c >> 4, cb = c & 15;  // cb: float4 index in row
                float4 xv = make_float4(0.f, 0.f, 0.f, 0.f);
                int m = m0 + row;
                if (m < M) xv = *reinterpret_cast<const float4*>(A + (size_t)m * 768 + aCol + cb * 4);
                ushort4 o;
                unsigned short hx = bhi(xv.x), hy = bhi(xv.y), hz = bhi(xv.z), hw = bhi(xv.w);
                if (low) {
                    o.x = blo(xv.x, hx); o.y = blo(xv.y, hy); o.z = blo(xv.z, hz); o.w = blo(xv.w, hw);
                } else {
                    o.x = hx; o.y = hy; o.z = hz; o.w = hw;
                }
                *(ushort4*)((char*)As + row * 128 + ((cb * 8) ^ ((row & 7) << 4))) = o;
            }
        } else {                                // bf16 ao: plain copy (dup via aCol)
#pragma unroll
            for (int i = 0; i < 4; i++) {
                int c = tid + i * 256;          // 1024 16B-chunks
                int row = c >> 3, cb = c & 7;
                bf16x8 v = *reinterpret_cast<const bf16x8*>(A + (size_t)(m0 + row) * 768 + aCol + cb * 8);
                *(bf16x8*)((char*)As + row * 128 + ((cb * 16) ^ ((row & 7) << 4))) = v;
            }
        }
        // ---- stage B (global_load_lds, pre-swizzled source) ----
#pragma unroll
        for (int j = 0; j < 4; j++) {
            int seg = j * 4 + w;                // 16 segs of 8 rows
            int row = seg * 8 + brs;
            gload_lds16(W + (size_t)(n0 + row) * 1536 + wCol + bcsw,
                        &Bs[seg * 512]);
        }
        __syncthreads();
        // ---- compute: 16 frags, 32 MFMA ----
        bf16x8 a[4][2], b[4][2];
#pragma unroll
        for (int mf = 0; mf < 4; mf++) {
            int row = wr * 64 + mf * 16 + lr;
            int sw = (row & 7) << 4;
            a[mf][0] = *(const bf16x8*)((const char*)As + row * 128 + ((lg * 16) ^ sw));
            a[mf][1] = *(const bf16x8*)((const char*)As + row * 128 + ((64 + lg * 16) ^ sw));
        }
#pragma unroll
        for (int nf = 0; nf < 4; nf++) {
            int row = wc * 64 + nf * 16 + lr;
            int sw = (row & 7) << 4;
            b[nf][0] = *(const bf16x8*)((const char*)Bs + row * 128 + ((lg * 16) ^ sw));
            b[nf][1] = *(const bf16x8*)((const char*)Bs + row * 128 + ((64 + lg * 16) ^ sw));
        }
#pragma unroll
        for (int mf = 0; mf < 4; mf++)
#pragma unroll
            for (int nf = 0; nf < 4; nf++) {
                acc[mf][nf] = __builtin_amdgcn_mfma_f32_16x16x32_bf16(a[mf][0], b[nf][0], acc[mf][nf], 0, 0, 0);
                acc[mf][nf] = __builtin_amdgcn_mfma_f32_16x16x32_bf16(a[mf][1], b[nf][1], acc[mf][nf], 0, 0, 0);
            }
    }
    // ---- epilogue: bias (+ LoRA), store ----
#pragma unroll
    for (int mf = 0; mf < 4; mf++) {
#pragma unroll
        for (int r = 0; r < 4; r++) {
            int m = m0 + wr * 64 + mf * 16 + lg * 4 + r;
            if (m < M) {
                float mr[8];
                if constexpr (LORA) {
                    float4 u0 = *reinterpret_cast<const float4*>(mid + (size_t)m * 8);
                    float4 u1 = *reinterpret_cast<const float4*>(mid + (size_t)m * 8 + 4);
                    mr[0] = u0.x; mr[1] = u0.y; mr[2] = u0.z; mr[3] = u0.w;
                    mr[4] = u1.x; mr[5] = u1.y; mr[6] = u1.z; mr[7] = u1.w;
                }
#pragma unroll
                for (int nf = 0; nf < 4; nf++) {
                    int n = n0 + wc * 64 + nf * 16 + lr;
                    float v = acc[mf][nf][r] + bias[n];
                    if constexpr (LORA) {
                        const float4 l0 = *reinterpret_cast<const float4*>(lb + (size_t)n * 8);
                        const float4 l1 = *reinterpret_cast<const float4*>(lb + (size_t)n * 8 + 4);
                        v += mr[0] * l0.x + mr[1] * l0.y + mr[2] * l0.z + mr[3] * l0.w
                           + mr[4] * l1.x + mr[5] * l1.y + mr[6] * l1.z + mr[7] * l1.w;
                    }
                    storeC(C + (size_t)m * N + n, v);
                }
            }
        }
    }
}

// ---------------- Fused per-frame attention, MFMA version ----------------
__global__ __launch_bounds__(256) void attn_kernel(const bf16* __restrict__ qkv,
        bf16* __restrict__ ao) {
    __shared__ bf16 Ks[208 * 64];      // [row][64]
    __shared__ bf16 Vt[64 * 208];      // [d][kk]
    __shared__ bf16 Ps[4][16 * 208];   // per-wave [q][kk]
    const int bb = blockIdx.x / NH;
    const int h = blockIdx.x % NH;
    const bf16* base = qkv + (size_t)bb * TP * N3;
    const int tid = threadIdx.x;
    const int w = tid >> 6, lane = tid & 63;
    const int lr = lane & 15, lg = lane >> 4;

    for (int idx = tid; idx < 208 * 16; idx += 256) {
        int row = idx >> 4, d4 = (idx & 15) * 4;
        ushort4 v = make_ushort4(0, 0, 0, 0);
        if (row < TP)
            v = *(const ushort4*)(base + (size_t)row * N3 + EDIM + h * 64 + d4);
        *(ushort4*)((char*)Ks + ((row * 128 + d4 * 2) ^ ((row & 7) << 4))) = v;
    }
    for (int g = w; g < 52; g += 4) {
        int kk0 = g * 4;
        int d = lane;
        const bf16* vb = base + (size_t)kk0 * N3 + 2 * EDIM + h * 64 + d;
        unsigned short t0 = 0, t1 = 0, t2 = 0, t3 = 0;
        if (kk0 + 0 < TP) t0 = *(const unsigned short*)(vb);
        if (kk0 + 1 < TP) t1 = *(const unsigned short*)(vb + N3);
        if (kk0 + 2 < TP) t2 = *(const unsigned short*)(vb + 2 * N3);
        if (kk0 + 3 < TP) t3 = *(const unsigned short*)(vb + 3 * N3);
        ushort4 v; v.x = t0; v.y = t1; v.z = t2; v.w = t3;
        *(ushort4*)((char*)Vt + ((d * 416 + kk0 * 2) ^ ((d & 7) << 4))) = v;
    }
    __syncthreads();

    bf16* Pw = &Ps[w][0];

    for (int qt = w; qt < 13; qt += 4) {
        int q = qt * 16 + lr; if (q > TP - 1) q = TP - 1;
        const bf16* qp = base + (size_t)q * N3 + h * 64 + lg * 8;
        bf16x8 qa0 = *(const bf16x8*)qp;
        bf16x8 qa1 = *(const bf16x8*)(qp + 32);

        f32x4 sf[13];
#pragma unroll
        for (int f = 0; f < 13; f++) {
            int row = f * 16 + lr;
            int swz = (row & 7) << 4;
            bf16x8 kb0 = *(const bf16x8*)((const char*)Ks + ((row * 128 + lg * 16) ^ swz));
            bf16x8 kb1 = *(const bf16x8*)((const char*)Ks + ((row * 128 + 64 + lg * 16) ^ swz));
            f32x4 c = {0.f, 0.f, 0.f, 0.f};
            c = __builtin_amdgcn_mfma_f32_16x16x32_bf16(qa0, kb0, c, 0, 0, 0);
            c = __builtin_amdgcn_mfma_f32_16x16x32_bf16(qa1, kb1, c, 0, 0, 0);
            sf[f] = c;
        }

        float mx[4] = {-1e30f, -1e30f, -1e30f, -1e30f};
#pragma unroll
        for (int f = 0; f < 13; f++) {
#pragma unroll
            for (int r = 0; r < 4; r++) {
                float s = sf[f][r] * SCALE;
                if (f == 12 && lr >= 5) s = -1e30f;
                sf[f][r] = s;
                mx[r] = fmaxf(mx[r], s);
            }
        }
#pragma unroll
        for (int off = 8; off >= 1; off >>= 1) {
#pragma unroll
            for (int r = 0; r < 4; r++) mx[r] = fmaxf(mx[r], __shfl_xor(mx[r], off, 64));
        }
        float lsum[4] = {0.f, 0.f, 0.f, 0.f};
#pragma unroll
        for (int f = 0; f < 13; f++) {
#pragma unroll
            for (int r = 0; r < 4; r++) {
                float e = __expf(sf[f][r] - mx[r]);
                sf[f][r] = e;
                lsum[r] += e;
            }
        }
#pragma unroll
        for (int off = 8; off >= 1; off >>= 1) {
#pragma unroll
            for (int r = 0; r < 4; r++) lsum[r] += __shfl_xor(lsum[r], off, 64);
        }
        float inv[4];
#pragma unroll
        for (int r = 0; r < 4; r++) inv[r] = 1.f / lsum[r];

#pragma unroll
        for (int f = 0; f < 13; f++) {
#pragma unroll
            for (int r = 0; r < 4; r++) {
                int row = lg * 4 + r;
                int col = f * 16 + lr;
                *(bf16*)((char*)Pw + ((row * 416 + col * 2) ^ ((row & 7) << 4))) =
                    __float2bfloat16(sf[f][r]);
            }
        }

        f32x4 of[4];
#pragma unroll
        for (int dt = 0; dt < 4; dt++) of[dt] = (f32x4){0.f, 0.f, 0.f, 0.f};
#pragma unroll
        for (int ks = 0; ks < 7; ks++) {
            int k0 = ks * 32 + lg * 8;
            bool ok = (k0 < 208);
            bf16x8 pa = {0, 0, 0, 0, 0, 0, 0, 0};
            if (ok)
                pa = *(const bf16x8*)((const char*)Pw + ((lr * 416 + k0 * 2) ^ ((lr & 7) << 4)));
#pragma unroll
            for (int dt = 0; dt < 4; dt++) {
                bf16x8 vb = {0, 0, 0, 0, 0, 0, 0, 0};
                if (ok) {
                    int d = dt * 16 + lr;
                    vb = *(const bf16x8*)((const char*)Vt + ((d * 416 + k0 * 2) ^ ((d & 7) << 4)));
                }
                of[dt] = __builtin_amdgcn_mfma_f32_16x16x32_bf16(pa, vb, of[dt], 0, 0, 0);
            }
        }

#pragma unroll
        for (int dt = 0; dt < 4; dt++) {
#pragma unroll
            for (int r = 0; r < 4; r++) {
                int qq = qt * 16 + lg * 4 + r;
                if (qq < TP)
                    ao[((size_t)bb * TP + qq) * EDIM + h * 64 + dt * 16 + lr] =
                        __float2bfloat16(of[dt][r] * inv[r]);
            }
        }
    }
}

// ---------------- Fused cross-frame CLS attention (flash-style online softmax) ----------
__global__ __launch_bounds__(256) void xattn_kernel(const bf16* __restrict__ qkv,
        float* __restrict__ x1p) {
    __shared__ float q1[NF][64];
    __shared__ bf16 Ks[128][64];
    __shared__ bf16 Vs[128][64];
    __shared__ float sc[NF][128];
    __shared__ float Oacc[NF][64];
    __shared__ float mrow[NF], lrow[NF], arow[NF];
    const int b = blockIdx.x / NH, h = blockIdx.x % NH;
    const int tid = threadIdx.x;
    for (int idx = tid; idx < NF * 64; idx += 256) {
        int f = idx >> 6, d = idx & 63;
        q1[f][d] = b2f(qkv[(size_t)((b * NF + f) * TP) * N3 + h * 64 + d]);
        Oacc[f][d] = 0.f;
    }
    if (tid < NF) { mrow[tid] = -1e30f; lrow[tid] = 0.f; }
    __syncthreads();
    const int w = tid >> 6, lane = tid & 63;
    for (int kk0 = 0; kk0 < KALL; kk0 += 128) {
        for (int idx = tid; idx < 128 * 16; idx += 256) {
            int r = idx >> 4, d4 = (idx & 15) * 4;
            int kk = kk0 + r;
            if (kk < KALL) {
                int f = kk / TP, pp = kk - f * TP;
                const bf16* src = qkv + (size_t)((b * NF + f) * TP + pp) * N3 + h * 64 + d4;
                *(ushort4*)&Ks[r][d4] = *(const ushort4*)(src + 768);
                *(ushort4*)&Vs[r][d4] = *(const ushort4*)(src + 1536);
            } else {
                ushort4 z; z.x = z.y = z.z = z.w = 0;
                *(ushort4*)&Ks[r][d4] = z;
                *(ushort4*)&Vs[r][d4] = z;
            }
        }
        __syncthreads();
        for (int idx = tid; idx < NF * 128; idx += 256) {
            int f = idx >> 7, r = idx & 127;
            float s = -1e30f;
            if (kk0 + r < KALL) {
                const bf16* kr = &Ks[r][0];
                float a = 0.f;
#pragma unroll
                for (int d2 = 0; d2 < 32; d2++) {
                    unsigned int u = *reinterpret_cast<const unsigned int*>(kr + 2 * d2);
                    a += q1[f][2 * d2] * __uint_as_float(u << 16);
                    a += q1[f][2 * d2 + 1] * __uint_as_float(u & 0xffff0000u);
                }
                s = a * SCALE;
            }
            sc[f][r] = s;
        }
        __syncthreads();
        for (int qi = 0; qi < 3; qi++) {
            int f = qi * 4 + w;
            float s0 = sc[f][lane], s1v = sc[f][lane + 64];
            float mx = fmaxf(s0, s1v);
#pragma unroll
            for (int off = 32; off >= 1; off >>= 1) mx = fmaxf(mx, __shfl_xor(mx, off, 64));
            float mold = mrow[f];
            float mnew = fmaxf(mold, mx);
            float e0 = __expf(s0 - mnew), e1 = __expf(s1v - mnew);
            float ls = e0 + e1;
#pragma unroll
            for (int off = 32; off >= 1; off >>= 1) ls += __shfl_xor(ls, off, 64);
            sc[f][lane] = e0; sc[f][lane + 64] = e1;
            if (lane == 0) {
                float alpha = __expf(mold - mnew);
                arow[f] = alpha;
                lrow[f] = lrow[f] * alpha + ls;
                mrow[f] = mnew;
            }
        }
        __syncthreads();
        for (int idx = tid; idx < NF * 64; idx += 256) {
            int f = idx >> 6, d = idx & 63;
            float o = Oacc[f][d] * arow[f];
#pragma unroll 4
            for (int r = 0; r < 128; r++)
                o += sc[f][r] * b2f(Vs[r][d]);
            Oacc[f][d] = o;
        }
        __syncthreads();
    }
    for (int idx = tid; idx < NF * 64; idx += 256) {
        int f = idx >> 6, d = idx & 63;
        x1p[(size_t)(b * NF + f) * EDIM + h * 64 + d] = Oacc[f][d] / lrow[f];
    }
}

// ---------------- CLS fixup: out[:,:,0,:] = MLP(out[:,:,0,:]) + x1p @ Wout^T + ob --------
__global__ __launch_bounds__(256) void cls_kernel(float* __restrict__ out,
        const float* __restrict__ x1p, const float* __restrict__ Wout, const float* __restrict__ ob,
        const float* __restrict__ dw, const float* __restrict__ db,
        const float* __restrict__ uw, const float* __restrict__ ub) {
    __shared__ float x0s[EDIM], x1s[EDIM], gs[8];
    const int bfi = blockIdx.x;
    float* row = out + (size_t)bfi * TP * EDIM;  // p = 0 row
    const int tid = threadIdx.x;
    for (int i = tid; i < EDIM; i += 256) {
        x0s[i] = row[i];
        x1s[i] = x1p[(size_t)bfi * EDIM + i];
    }
    __syncthreads();
    {
        int r = tid >> 5, sl = tid & 31;
        float pr = 0.f;
        for (int e = sl; e < EDIM; e += 32) pr += x0s[e] * dw[r * EDIM + e];
#pragma unroll
        for (int off = 16; off >= 1; off >>= 1) pr += __shfl_xor(pr, off, 64);
        if (sl == 0) gs[r] = pr + db[r];
    }
    __syncthreads();
    float act[8];
#pragma unroll
    for (int r = 0; r < 8; r++) { float g = gs[r]; act[r] = g / (1.f + __expf(-1.702f * g)); }
    for (int j = tid; j < EDIM; j += 256) {
        float y = ub[j] + ob[j];
        const float4 u0 = *reinterpret_cast<const float4*>(uw + (size_t)j * 8);
        const float4 u1 = *reinterpret_cast<const float4*>(uw + (size_t)j * 8 + 4);
        y += act[0] * u0.x + act[1] * u0.y + act[2] * u0.z + act[3] * u0.w
           + act[4] * u1.x + act[5] * u1.y + act[6] * u1.z + act[7] * u1.w;
        const float* wr = Wout + (size_t)j * EDIM;
        float s = 0.f;
        for (int e = 0; e < EDIM; e += 4) {
            float4 wv = *reinterpret_cast<const float4*>(wr + e);
            s += x1s[e] * wv.x + x1s[e + 1] * wv.y + x1s[e + 2] * wv.z + x1s[e + 3] * wv.w;
        }
        y += s;
        row[j] = y;
    }
}

extern "C" void kernel_launch(void* const* d_in, const int* in_sizes, int n_in,
                              void* d_out, int out_size, void* d_ws, size_t ws_size,
                              hipStream_t stream) {
    (void)in_sizes; (void)n_in; (void)out_size; (void)ws_size;
    const float* x   = (const float*)d_in[0];
    const float* ipw = (const float*)d_in[1];
    const float* ipb = (const float*)d_in[2];
    const float* opw = (const float*)d_in[3];
    const float* opb = (const float*)d_in[4];
    const float* la  = (const float*)d_in[5];
    const float* lb  = (const float*)d_in[6];
    const float* dw  = (const float*)d_in[7];
    const float* db  = (const float*)d_in[8];
    const float* uw  = (const float*)d_in[9];
    const float* ub  = (const float*)d_in[10];
    float* out = (float*)d_out;   // fp32 output per reference dtype

    // workspace: qkv 174.3 + ao 58.2 + W1 7.1 + W2 2.4 + mid 1.2 + x1p 0.6 = ~243.8 MB
    char* wsb = (char*)d_ws;
    bf16* qkv = (bf16*)wsb;                       wsb += (size_t)NT * N3 * sizeof(bf16);
    bf16* ao  = (bf16*)wsb;                       wsb += (size_t)MPAD * EDIM * sizeof(bf16);
    bf16* W1  = (bf16*)wsb;                       wsb += (size_t)N3 * 1536 * sizeof(bf16);
    bf16* W2  = (bf16*)wsb;                       wsb += (size_t)EDIM * 1536 * sizeof(bf16);
    float* mid = (float*)wsb;                     wsb += (size_t)NT * 8 * sizeof(float);
    float* x1p = (float*)wsb;                     wsb += (size_t)NB * NF * EDIM * sizeof(float);

    split_w_kernel<<<(N3 * 192 + 255) / 256, 256, 0, stream>>>(ipw, W1, N3);
    split_w_kernel<<<(EDIM * 192 + 255) / 256, 256, 0, stream>>>(opw, W2, EDIM);
    lora_mid_kernel<<<NT / 4, 256, 0, stream>>>(x, la, mid);
    // QKV: virtual K = 2304 (hi*Whi + hi*Wlo + lo*Whi)
    mfma_gemm_kernel<float, bf16, true><<<dim3(N3 / 128, MPAD / 128), 256, 0, stream>>>(
        x, W1, ipb, mid, lb, qkv, NT, N3, 2304);
    attn_kernel<<<192 * NH, 256, 0, stream>>>(qkv, ao);
    xattn_kernel<<<NB * NH, 256, 0, stream>>>(qkv, x1p);
    // out-proj: virtual K = 1536 (ao*Whi + ao*Wlo)
    mfma_gemm_kernel<bf16, float, false><<<dim3(EDIM / 128, MPAD / 128), 256, 0, stream>>>(
        ao, W2, opb, nullptr, nullptr, out, NT, EDIM, 1536);
    cls_kernel<<<NB * NF, 256, 0, stream>>>(out, x1p, opw, opb, dw, db, uw, ub);
}

// Round 3
// 1558.341 us; speedup vs baseline: 3.1020x; 1.6149x over previous
//
#include <hip/hip_runtime.h>
#include <hip/hip_bf16.h>

typedef __hip_bfloat16 bf16;
typedef __attribute__((ext_vector_type(8))) short bf16x8;   // 8 bf16 = 4 VGPRs (MFMA A/B frag)
typedef __attribute__((ext_vector_type(4))) float f32x4;    // MFMA C/D frag

#define NT   37824   // total tokens = 192*197
#define MPAD 37888   // 296*128 (padded rows for 128-tile GEMM)
#define EDIM 768
#define N3   2304
#define TP   197     // tokens per frame
#define NB   16
#define NF   12
#define NH   12
#define HD   64
#define SCALE 0.125f
#define KALL 2364    // 12*197

__device__ __forceinline__ float bits2f(unsigned short u) {
    unsigned int v = ((unsigned int)u) << 16;
    return __uint_as_float(v);
}
__device__ __forceinline__ float b2f(bf16 v) { return __bfloat162float(v); }

__device__ __forceinline__ unsigned short bhi(float x) {
    union { bf16 b; unsigned short u; } cv; cv.b = __float2bfloat16(x); return cv.u;
}
__device__ __forceinline__ unsigned short blo(float x, unsigned short h) {
    float hf = __uint_as_float(((unsigned int)h) << 16);
    union { bf16 b; unsigned short u; } cv; cv.b = __float2bfloat16(x - hf); return cv.u;
}

__device__ __forceinline__ void storeC(float* p, float v) { *p = v; }
__device__ __forceinline__ void storeC(bf16* p, float v) { *p = __float2bfloat16(v); }

// async global->LDS, 16B per lane; lds dest = wave-uniform base + lane*16
__device__ __forceinline__ void gload_lds16(const bf16* g, bf16* l) {
    __builtin_amdgcn_global_load_lds(
        (const __attribute__((address_space(1))) void*)g,
        (__attribute__((address_space(3))) void*)l,
        16, 0, 0);
}

// ---------------- K1: mid = x @ lora_a^T  (NT x 8), fp32 in ----------------
__global__ __launch_bounds__(256) void lora_mid_kernel(const float* __restrict__ x,
        const float* __restrict__ la, float* __restrict__ mid) {
    int t = blockIdx.x * 4 + (threadIdx.x >> 6);
    int lane = threadIdx.x & 63;
    if (t >= NT) return;
    float acc[8];
#pragma unroll
    for (int r = 0; r < 8; r++) acc[r] = 0.f;
    const float* xr = x + (size_t)t * EDIM;
    for (int e = lane; e < EDIM; e += 64) {
        float xv = xr[e];
#pragma unroll
        for (int r = 0; r < 8; r++) acc[r] += xv * la[r * EDIM + e];
    }
#pragma unroll
    for (int r = 0; r < 8; r++) {
        float v = acc[r];
#pragma unroll
        for (int off = 32; off >= 1; off >>= 1) v += __shfl_xor(v, off, 64);
        if (lane == 0) mid[(size_t)t * 8 + r] = v;
    }
}

// ---- split fp32 rows x 768 -> bf16 [hi | lo] rows x 1536 (used for W and for x) --------
__global__ __launch_bounds__(256) void split_w_kernel(const float* __restrict__ w,
        bf16* __restrict__ o, int rows) {
    int idx = blockIdx.x * 256 + threadIdx.x;
    int total = rows * 192;                        // 768/4 float4-chunks per row
    if (idx >= total) return;
    int r = idx / 192, c = (idx - r * 192) * 4;
    float4 v = *reinterpret_cast<const float4*>(w + (size_t)r * 768 + c);
    ushort4 hi, lo;
    hi.x = bhi(v.x); hi.y = bhi(v.y); hi.z = bhi(v.z); hi.w = bhi(v.w);
    lo.x = blo(v.x, hi.x); lo.y = blo(v.y, hi.y); lo.z = blo(v.z, hi.z); lo.w = blo(v.w, hi.w);
    *(ushort4*)(o + (size_t)r * 1536 + c) = hi;
    *(ushort4*)(o + (size_t)r * 1536 + 768 + c) = lo;
}

// ---------------- MFMA GEMM: C = A @ Wsplit^T + bias (+ mid @ lora_b^T) ----------------
// Virtual-K decomposition (fp32 accuracy from bf16 MFMA):
//   QKV  (KV=2304, A = xs [x_hi | x_lo], lda=1536): x_hi@Whi + x_hi@Wlo + x_lo@Whi
//   proj (KV=1536, A = ao,               lda=768 ): ao@Whi + ao@Wlo
//   aOff = k0>=768 ? k0-768 : k0   (hi for passes 1-2, lo section for pass 3)
//   wOff = k0 mod 1536             (W pre-split bf16 [W_hi | W_lo], stride 1536)
// m97 structure: 128x128 tile, BK=64, 4 waves (2x2 of 64x64), both operands staged
// via global_load_lds(16B). LDS [128 rows][64 bf16] XOR-swizzled byte^=((row&7)<<4)
// realized by inverse-swizzling the per-lane GLOBAL source (rule #21): lane l of the
// 8-row segment loads col-chunk (l&7)^(l>>3) of row (l>>3) -> linear LDS dest holds
// swizzled layout; reads use the same involution. Verified 0 bank conflicts (r2).
template <typename OT, bool LORA>
__global__ __launch_bounds__(256) void mfma_gemm_kernel(const bf16* __restrict__ A, int lda,
        const bf16* __restrict__ W, const float* __restrict__ bias,
        const float* __restrict__ mid, const float* __restrict__ lb,
        OT* __restrict__ C, int M, int N, int KV) {
    __shared__ bf16 As[128 * 64];
    __shared__ bf16 Bs[128 * 64];
    const int tid = threadIdx.x;
    const int w = tid >> 6, lane = tid & 63;
    const int lr = lane & 15, lg = lane >> 4;
    const int wr = w >> 1, wc = w & 1;

    // bijective XCD-chunk swizzle (nwg % 8 == 0 for both launches)
    const int gx = gridDim.x;
    const int nwg = gx * gridDim.y;
    const int flat = blockIdx.y * gx + blockIdx.x;
    const int cpx = nwg >> 3;
    const int lid = (flat & 7) * cpx + (flat >> 3);
    const int m0 = (lid / gx) * 128, n0 = (lid % gx) * 128;

    f32x4 acc[4][4];
#pragma unroll
    for (int i = 0; i < 4; i++)
#pragma unroll
        for (int j = 0; j < 4; j++) acc[i][j] = (f32x4){0.f, 0.f, 0.f, 0.f};

    // staging source swizzle (rule #21)
    const int brs = lane >> 3;                 // row within 8-row segment
    const int bcsw = ((lane & 7) ^ brs) << 3;  // swizzled col offset, elems (16B chunks)

    for (int k0 = 0; k0 < KV; k0 += 64) {
        const int aOff = (k0 >= 768) ? k0 - 768 : k0;
        const int wOff = (k0 >= 1536) ? k0 - 1536 : k0;
        __syncthreads();
#pragma unroll
        for (int j = 0; j < 4; j++) {
            int seg = j * 4 + w;                // 16 segs of 8 rows each
            int row = seg * 8 + brs;
            gload_lds16(A + (size_t)(m0 + row) * lda + aOff + bcsw, &As[seg * 512]);
            gload_lds16(W + (size_t)(n0 + row) * 1536 + wOff + bcsw, &Bs[seg * 512]);
        }
        __syncthreads();
        // ---- compute: 16 frags, 32 MFMA ----
        bf16x8 a[4][2], b[4][2];
#pragma unroll
        for (int mf = 0; mf < 4; mf++) {
            int row = wr * 64 + mf * 16 + lr;
            int sw = (row & 7) << 4;
            a[mf][0] = *(const bf16x8*)((const char*)As + row * 128 + ((lg * 16) ^ sw));
            a[mf][1] = *(const bf16x8*)((const char*)As + row * 128 + ((64 + lg * 16) ^ sw));
        }
#pragma unroll
        for (int nf = 0; nf < 4; nf++) {
            int row = wc * 64 + nf * 16 + lr;
            int sw = (row & 7) << 4;
            b[nf][0] = *(const bf16x8*)((const char*)Bs + row * 128 + ((lg * 16) ^ sw));
            b[nf][1] = *(const bf16x8*)((const char*)Bs + row * 128 + ((64 + lg * 16) ^ sw));
        }
#pragma unroll
        for (int mf = 0; mf < 4; mf++)
#pragma unroll
            for (int nf = 0; nf < 4; nf++) {
                acc[mf][nf] = __builtin_amdgcn_mfma_f32_16x16x32_bf16(a[mf][0], b[nf][0], acc[mf][nf], 0, 0, 0);
                acc[mf][nf] = __builtin_amdgcn_mfma_f32_16x16x32_bf16(a[mf][1], b[nf][1], acc[mf][nf], 0, 0, 0);
            }
    }
    // ---- epilogue: bias (+ LoRA), store ----
#pragma unroll
    for (int mf = 0; mf < 4; mf++) {
#pragma unroll
        for (int r = 0; r < 4; r++) {
            int m = m0 + wr * 64 + mf * 16 + lg * 4 + r;
            if (m < M) {
                float mr[8];
                if constexpr (LORA) {
                    float4 u0 = *reinterpret_cast<const float4*>(mid + (size_t)m * 8);
                    float4 u1 = *reinterpret_cast<const float4*>(mid + (size_t)m * 8 + 4);
                    mr[0] = u0.x; mr[1] = u0.y; mr[2] = u0.z; mr[3] = u0.w;
                    mr[4] = u1.x; mr[5] = u1.y; mr[6] = u1.z; mr[7] = u1.w;
                }
#pragma unroll
                for (int nf = 0; nf < 4; nf++) {
                    int n = n0 + wc * 64 + nf * 16 + lr;
                    float v = acc[mf][nf][r] + bias[n];
                    if constexpr (LORA) {
                        const float4 l0 = *reinterpret_cast<const float4*>(lb + (size_t)n * 8);
                        const float4 l1 = *reinterpret_cast<const float4*>(lb + (size_t)n * 8 + 4);
                        v += mr[0] * l0.x + mr[1] * l0.y + mr[2] * l0.z + mr[3] * l0.w
                           + mr[4] * l1.x + mr[5] * l1.y + mr[6] * l1.z + mr[7] * l1.w;
                    }
                    storeC(C + (size_t)m * N + n, v);
                }
            }
        }
    }
}

// ---------------- Fused per-frame attention, MFMA version ----------------
__global__ __launch_bounds__(256) void attn_kernel(const bf16* __restrict__ qkv,
        bf16* __restrict__ ao) {
    __shared__ bf16 Ks[208 * 64];      // [row][64]
    __shared__ bf16 Vt[64 * 208];      // [d][kk]
    __shared__ bf16 Ps[4][16 * 208];   // per-wave [q][kk]
    const int bb = blockIdx.x / NH;
    const int h = blockIdx.x % NH;
    const bf16* base = qkv + (size_t)bb * TP * N3;
    const int tid = threadIdx.x;
    const int w = tid >> 6, lane = tid & 63;
    const int lr = lane & 15, lg = lane >> 4;

    for (int idx = tid; idx < 208 * 16; idx += 256) {
        int row = idx >> 4, d4 = (idx & 15) * 4;
        ushort4 v = make_ushort4(0, 0, 0, 0);
        if (row < TP)
            v = *(const ushort4*)(base + (size_t)row * N3 + EDIM + h * 64 + d4);
        *(ushort4*)((char*)Ks + ((row * 128 + d4 * 2) ^ ((row & 7) << 4))) = v;
    }
    for (int g = w; g < 52; g += 4) {
        int kk0 = g * 4;
        int d = lane;
        const bf16* vb = base + (size_t)kk0 * N3 + 2 * EDIM + h * 64 + d;
        unsigned short t0 = 0, t1 = 0, t2 = 0, t3 = 0;
        if (kk0 + 0 < TP) t0 = *(const unsigned short*)(vb);
        if (kk0 + 1 < TP) t1 = *(const unsigned short*)(vb + N3);
        if (kk0 + 2 < TP) t2 = *(const unsigned short*)(vb + 2 * N3);
        if (kk0 + 3 < TP) t3 = *(const unsigned short*)(vb + 3 * N3);
        ushort4 v; v.x = t0; v.y = t1; v.z = t2; v.w = t3;
        *(ushort4*)((char*)Vt + ((d * 416 + kk0 * 2) ^ ((d & 7) << 4))) = v;
    }
    __syncthreads();

    bf16* Pw = &Ps[w][0];

    for (int qt = w; qt < 13; qt += 4) {
        int q = qt * 16 + lr; if (q > TP - 1) q = TP - 1;
        const bf16* qp = base + (size_t)q * N3 + h * 64 + lg * 8;
        bf16x8 qa0 = *(const bf16x8*)qp;
        bf16x8 qa1 = *(const bf16x8*)(qp + 32);

        f32x4 sf[13];
#pragma unroll
        for (int f = 0; f < 13; f++) {
            int row = f * 16 + lr;
            int swz = (row & 7) << 4;
            bf16x8 kb0 = *(const bf16x8*)((const char*)Ks + ((row * 128 + lg * 16) ^ swz));
            bf16x8 kb1 = *(const bf16x8*)((const char*)Ks + ((row * 128 + 64 + lg * 16) ^ swz));
            f32x4 c = {0.f, 0.f, 0.f, 0.f};
            c = __builtin_amdgcn_mfma_f32_16x16x32_bf16(qa0, kb0, c, 0, 0, 0);
            c = __builtin_amdgcn_mfma_f32_16x16x32_bf16(qa1, kb1, c, 0, 0, 0);
            sf[f] = c;
        }

        float mx[4] = {-1e30f, -1e30f, -1e30f, -1e30f};
#pragma unroll
        for (int f = 0; f < 13; f++) {
#pragma unroll
            for (int r = 0; r < 4; r++) {
                float s = sf[f][r] * SCALE;
                if (f == 12 && lr >= 5) s = -1e30f;
                sf[f][r] = s;
                mx[r] = fmaxf(mx[r], s);
            }
        }
#pragma unroll
        for (int off = 8; off >= 1; off >>= 1) {
#pragma unroll
            for (int r = 0; r < 4; r++) mx[r] = fmaxf(mx[r], __shfl_xor(mx[r], off, 64));
        }
        float lsum[4] = {0.f, 0.f, 0.f, 0.f};
#pragma unroll
        for (int f = 0; f < 13; f++) {
#pragma unroll
            for (int r = 0; r < 4; r++) {
                float e = __expf(sf[f][r] - mx[r]);
                sf[f][r] = e;
                lsum[r] += e;
            }
        }
#pragma unroll
        for (int off = 8; off >= 1; off >>= 1) {
#pragma unroll
            for (int r = 0; r < 4; r++) lsum[r] += __shfl_xor(lsum[r], off, 64);
        }
        float inv[4];
#pragma unroll
        for (int r = 0; r < 4; r++) inv[r] = 1.f / lsum[r];

#pragma unroll
        for (int f = 0; f < 13; f++) {
#pragma unroll
            for (int r = 0; r < 4; r++) {
                int row = lg * 4 + r;
                int col = f * 16 + lr;
                *(bf16*)((char*)Pw + ((row * 416 + col * 2) ^ ((row & 7) << 4))) =
                    __float2bfloat16(sf[f][r]);
            }
        }

        f32x4 of[4];
#pragma unroll
        for (int dt = 0; dt < 4; dt++) of[dt] = (f32x4){0.f, 0.f, 0.f, 0.f};
#pragma unroll
        for (int ks = 0; ks < 7; ks++) {
            int k0 = ks * 32 + lg * 8;
            bool ok = (k0 < 208);
            bf16x8 pa = {0, 0, 0, 0, 0, 0, 0, 0};
            if (ok)
                pa = *(const bf16x8*)((const char*)Pw + ((lr * 416 + k0 * 2) ^ ((lr & 7) << 4)));
#pragma unroll
            for (int dt = 0; dt < 4; dt++) {
                bf16x8 vb = {0, 0, 0, 0, 0, 0, 0, 0};
                if (ok) {
                    int d = dt * 16 + lr;
                    vb = *(const bf16x8*)((const char*)Vt + ((d * 416 + k0 * 2) ^ ((d & 7) << 4)));
                }
                of[dt] = __builtin_amdgcn_mfma_f32_16x16x32_bf16(pa, vb, of[dt], 0, 0, 0);
            }
        }

#pragma unroll
        for (int dt = 0; dt < 4; dt++) {
#pragma unroll
            for (int r = 0; r < 4; r++) {
                int qq = qt * 16 + lg * 4 + r;
                if (qq < TP)
                    ao[((size_t)bb * TP + qq) * EDIM + h * 64 + dt * 16 + lr] =
                        __float2bfloat16(of[dt][r] * inv[r]);
            }
        }
    }
}

// ---------------- Fused cross-frame CLS attention (flash-style online softmax) ----------
__global__ __launch_bounds__(256) void xattn_kernel(const bf16* __restrict__ qkv,
        float* __restrict__ x1p) {
    __shared__ float q1[NF][64];
    __shared__ bf16 Ks[128][64];
    __shared__ bf16 Vs[128][64];
    __shared__ float sc[NF][128];
    __shared__ float Oacc[NF][64];
    __shared__ float mrow[NF], lrow[NF], arow[NF];
    const int b = blockIdx.x / NH, h = blockIdx.x % NH;
    const int tid = threadIdx.x;
    for (int idx = tid; idx < NF * 64; idx += 256) {
        int f = idx >> 6, d = idx & 63;
        q1[f][d] = b2f(qkv[(size_t)((b * NF + f) * TP) * N3 + h * 64 + d]);
        Oacc[f][d] = 0.f;
    }
    if (tid < NF) { mrow[tid] = -1e30f; lrow[tid] = 0.f; }
    __syncthreads();
    const int w = tid >> 6, lane = tid & 63;
    for (int kk0 = 0; kk0 < KALL; kk0 += 128) {
        for (int idx = tid; idx < 128 * 16; idx += 256) {
            int r = idx >> 4, d4 = (idx & 15) * 4;
            int kk = kk0 + r;
            if (kk < KALL) {
                int f = kk / TP, pp = kk - f * TP;
                const bf16* src = qkv + (size_t)((b * NF + f) * TP + pp) * N3 + h * 64 + d4;
                *(ushort4*)&Ks[r][d4] = *(const ushort4*)(src + 768);
                *(ushort4*)&Vs[r][d4] = *(const ushort4*)(src + 1536);
            } else {
                ushort4 z; z.x = z.y = z.z = z.w = 0;
                *(ushort4*)&Ks[r][d4] = z;
                *(ushort4*)&Vs[r][d4] = z;
            }
        }
        __syncthreads();
        for (int idx = tid; idx < NF * 128; idx += 256) {
            int f = idx >> 7, r = idx & 127;
            float s = -1e30f;
            if (kk0 + r < KALL) {
                const bf16* kr = &Ks[r][0];
                float a = 0.f;
#pragma unroll
                for (int d2 = 0; d2 < 32; d2++) {
                    unsigned int u = *reinterpret_cast<const unsigned int*>(kr + 2 * d2);
                    a += q1[f][2 * d2] * __uint_as_float(u << 16);
                    a += q1[f][2 * d2 + 1] * __uint_as_float(u & 0xffff0000u);
                }
                s = a * SCALE;
            }
            sc[f][r] = s;
        }
        __syncthreads();
        for (int qi = 0; qi < 3; qi++) {
            int f = qi * 4 + w;
            float s0 = sc[f][lane], s1v = sc[f][lane + 64];
            float mx = fmaxf(s0, s1v);
#pragma unroll
            for (int off = 32; off >= 1; off >>= 1) mx = fmaxf(mx, __shfl_xor(mx, off, 64));
            float mold = mrow[f];
            float mnew = fmaxf(mold, mx);
            float e0 = __expf(s0 - mnew), e1 = __expf(s1v - mnew);
            float ls = e0 + e1;
#pragma unroll
            for (int off = 32; off >= 1; off >>= 1) ls += __shfl_xor(ls, off, 64);
            sc[f][lane] = e0; sc[f][lane + 64] = e1;
            if (lane == 0) {
                float alpha = __expf(mold - mnew);
                arow[f] = alpha;
                lrow[f] = lrow[f] * alpha + ls;
                mrow[f] = mnew;
            }
        }
        __syncthreads();
        for (int idx = tid; idx < NF * 64; idx += 256) {
            int f = idx >> 6, d = idx & 63;
            float o = Oacc[f][d] * arow[f];
#pragma unroll 4
            for (int r = 0; r < 128; r++)
                o += sc[f][r] * b2f(Vs[r][d]);
            Oacc[f][d] = o;
        }
        __syncthreads();
    }
    for (int idx = tid; idx < NF * 64; idx += 256) {
        int f = idx >> 6, d = idx & 63;
        x1p[(size_t)(b * NF + f) * EDIM + h * 64 + d] = Oacc[f][d] / lrow[f];
    }
}

// ---------------- CLS fixup: out[:,:,0,:] = MLP(out[:,:,0,:]) + x1p @ Wout^T + ob --------
__global__ __launch_bounds__(256) void cls_kernel(float* __restrict__ out,
        const float* __restrict__ x1p, const float* __restrict__ Wout, const float* __restrict__ ob,
        const float* __restrict__ dw, const float* __restrict__ db,
        const float* __restrict__ uw, const float* __restrict__ ub) {
    __shared__ float x0s[EDIM], x1s[EDIM], gs[8];
    const int bfi = blockIdx.x;
    float* row = out + (size_t)bfi * TP * EDIM;  // p = 0 row
    const int tid = threadIdx.x;
    for (int i = tid; i < EDIM; i += 256) {
        x0s[i] = row[i];
        x1s[i] = x1p[(size_t)bfi * EDIM + i];
    }
    __syncthreads();
    {
        int r = tid >> 5, sl = tid & 31;
        float pr = 0.f;
        for (int e = sl; e < EDIM; e += 32) pr += x0s[e] * dw[r * EDIM + e];
#pragma unroll
        for (int off = 16; off >= 1; off >>= 1) pr += __shfl_xor(pr, off, 64);
        if (sl == 0) gs[r] = pr + db[r];
    }
    __syncthreads();
    float act[8];
#pragma unroll
    for (int r = 0; r < 8; r++) { float g = gs[r]; act[r] = g / (1.f + __expf(-1.702f * g)); }
    for (int j = tid; j < EDIM; j += 256) {
        float y = ub[j] + ob[j];
        const float4 u0 = *reinterpret_cast<const float4*>(uw + (size_t)j * 8);
        const float4 u1 = *reinterpret_cast<const float4*>(uw + (size_t)j * 8 + 4);
        y += act[0] * u0.x + act[1] * u0.y + act[2] * u0.z + act[3] * u0.w
           + act[4] * u1.x + act[5] * u1.y + act[6] * u1.z + act[7] * u1.w;
        const float* wr = Wout + (size_t)j * EDIM;
        float s = 0.f;
        for (int e = 0; e < EDIM; e += 4) {
            float4 wv = *reinterpret_cast<const float4*>(wr + e);
            s += x1s[e] * wv.x + x1s[e + 1] * wv.y + x1s[e + 2] * wv.z + x1s[e + 3] * wv.w;
        }
        y += s;
        row[j] = y;
    }
}

extern "C" void kernel_launch(void* const* d_in, const int* in_sizes, int n_in,
                              void* d_out, int out_size, void* d_ws, size_t ws_size,
                              hipStream_t stream) {
    (void)in_sizes; (void)n_in; (void)out_size; (void)ws_size;
    const float* x   = (const float*)d_in[0];
    const float* ipw = (const float*)d_in[1];
    const float* ipb = (const float*)d_in[2];
    const float* opw = (const float*)d_in[3];
    const float* opb = (const float*)d_in[4];
    const float* la  = (const float*)d_in[5];
    const float* lb  = (const float*)d_in[6];
    const float* dw  = (const float*)d_in[7];
    const float* db  = (const float*)d_in[8];
    const float* uw  = (const float*)d_in[9];
    const float* ub  = (const float*)d_in[10];
    float* out = (float*)d_out;   // fp32 output per reference dtype

    // workspace: qkv 174.3 + ao 58.2 + xs 116.4 + W1 7.1 + W2 2.4 + mid 1.2 + x1p 0.6 ≈ 360 MB
    char* wsb = (char*)d_ws;
    bf16* qkv = (bf16*)wsb;                       wsb += (size_t)NT * N3 * sizeof(bf16);
    bf16* ao  = (bf16*)wsb;                       wsb += (size_t)MPAD * EDIM * sizeof(bf16);
    bf16* xs  = (bf16*)wsb;                       wsb += (size_t)MPAD * 1536 * sizeof(bf16);
    bf16* W1  = (bf16*)wsb;                       wsb += (size_t)N3 * 1536 * sizeof(bf16);
    bf16* W2  = (bf16*)wsb;                       wsb += (size_t)EDIM * 1536 * sizeof(bf16);
    float* mid = (float*)wsb;                     wsb += (size_t)NT * 8 * sizeof(float);
    float* x1p = (float*)wsb;                     wsb += (size_t)NB * NF * EDIM * sizeof(float);

    split_w_kernel<<<(N3 * 192 + 255) / 256, 256, 0, stream>>>(ipw, W1, N3);
    split_w_kernel<<<(EDIM * 192 + 255) / 256, 256, 0, stream>>>(opw, W2, EDIM);
    split_w_kernel<<<(NT * 192 + 255) / 256, 256, 0, stream>>>(x, xs, NT);
    lora_mid_kernel<<<NT / 4, 256, 0, stream>>>(x, la, mid);
    // QKV: virtual K = 2304 (hi*Whi + hi*Wlo + lo*Whi)
    mfma_gemm_kernel<bf16, true><<<dim3(N3 / 128, MPAD / 128), 256, 0, stream>>>(
        xs, 1536, W1, ipb, mid, lb, qkv, NT, N3, 2304);
    attn_kernel<<<192 * NH, 256, 0, stream>>>(qkv, ao);
    xattn_kernel<<<NB * NH, 256, 0, stream>>>(qkv, x1p);
    // out-proj: virtual K = 1536 (ao*Whi + ao*Wlo)
    mfma_gemm_kernel<float, false><<<dim3(EDIM / 128, MPAD / 128), 256, 0, stream>>>(
        ao, 768, W2, opb, nullptr, nullptr, out, NT, EDIM, 1536);
    cls_kernel<<<NB * NF, 256, 0, stream>>>(out, x1p, opw, opb, dw, db, uw, ub);
}

// Round 4
// 1541.168 us; speedup vs baseline: 3.1366x; 1.0111x over previous
//
#include <hip/hip_runtime.h>
#include <hip/hip_bf16.h>

typedef __hip_bfloat16 bf16;
typedef __attribute__((ext_vector_type(8))) short bf16x8;   // 8 bf16 = 4 VGPRs (MFMA A/B frag)
typedef __attribute__((ext_vector_type(4))) float f32x4;    // MFMA C/D frag

#define NT   37824   // total tokens = 192*197
#define MPAD 37888   // 296*128 (padded rows for 128-tile GEMM)
#define EDIM 768
#define N3   2304
#define TP   197     // tokens per frame
#define NB   16
#define NF   12
#define NH   12
#define HD   64
#define SCALE 0.125f
#define KALL 2364    // 12*197

__device__ __forceinline__ float bits2f(unsigned short u) {
    unsigned int v = ((unsigned int)u) << 16;
    return __uint_as_float(v);
}
__device__ __forceinline__ float b2f(bf16 v) { return __bfloat162float(v); }

__device__ __forceinline__ unsigned short bhi(float x) {
    union { bf16 b; unsigned short u; } cv; cv.b = __float2bfloat16(x); return cv.u;
}
__device__ __forceinline__ unsigned short blo(float x, unsigned short h) {
    float hf = __uint_as_float(((unsigned int)h) << 16);
    union { bf16 b; unsigned short u; } cv; cv.b = __float2bfloat16(x - hf); return cv.u;
}

__device__ __forceinline__ void storeC(float* p, float v) { *p = v; }
__device__ __forceinline__ void storeC(bf16* p, float v) { *p = __float2bfloat16(v); }

// async global->LDS, 16B per lane; lds dest = wave-uniform base + lane*16
__device__ __forceinline__ void gload_lds16(const bf16* g, bf16* l) {
    __builtin_amdgcn_global_load_lds(
        (const __attribute__((address_space(1))) void*)g,
        (__attribute__((address_space(3))) void*)l,
        16, 0, 0);
}

// ---------------- K1: mid = x @ lora_a^T  (NT x 8), fp32 in ----------------
__global__ __launch_bounds__(256) void lora_mid_kernel(const float* __restrict__ x,
        const float* __restrict__ la, float* __restrict__ mid) {
    int t = blockIdx.x * 4 + (threadIdx.x >> 6);
    int lane = threadIdx.x & 63;
    if (t >= NT) return;
    float acc[8];
#pragma unroll
    for (int r = 0; r < 8; r++) acc[r] = 0.f;
    const float* xr = x + (size_t)t * EDIM;
    for (int e = lane; e < EDIM; e += 64) {
        float xv = xr[e];
#pragma unroll
        for (int r = 0; r < 8; r++) acc[r] += xv * la[r * EDIM + e];
    }
#pragma unroll
    for (int r = 0; r < 8; r++) {
        float v = acc[r];
#pragma unroll
        for (int off = 32; off >= 1; off >>= 1) v += __shfl_xor(v, off, 64);
        if (lane == 0) mid[(size_t)t * 8 + r] = v;
    }
}

// ---- split fp32 rows x 768 -> bf16 [hi | lo] rows x 1536 (used for W and for x) --------
__global__ __launch_bounds__(256) void split_w_kernel(const float* __restrict__ w,
        bf16* __restrict__ o, int rows) {
    int idx = blockIdx.x * 256 + threadIdx.x;
    int total = rows * 192;                        // 768/4 float4-chunks per row
    if (idx >= total) return;
    int r = idx / 192, c = (idx - r * 192) * 4;
    float4 v = *reinterpret_cast<const float4*>(w + (size_t)r * 768 + c);
    ushort4 hi, lo;
    hi.x = bhi(v.x); hi.y = bhi(v.y); hi.z = bhi(v.z); hi.w = bhi(v.w);
    lo.x = blo(v.x, hi.x); lo.y = blo(v.y, hi.y); lo.z = blo(v.z, hi.z); lo.w = blo(v.w, hi.w);
    *(ushort4*)(o + (size_t)r * 1536 + c) = hi;
    *(ushort4*)(o + (size_t)r * 1536 + 768 + c) = lo;
}

// ---------------- MFMA GEMM: C = A @ Wsplit^T + bias (+ mid @ lora_b^T) ----------------
// Virtual-K decomposition (fp32 accuracy from bf16 MFMA):
//   QKV  (KV=2304, A = xs [x_hi | x_lo], lda=1536): x_hi@Whi + x_hi@Wlo + x_lo@Whi
//   proj (KV=1536, A = ao,               lda=768 ): ao@Whi + ao@Wlo
// 2-PHASE PIPELINE (T3-min recipe): double-buffered LDS; per K-step issue next
// tile's global_load_lds FIRST, then ds_read+MFMA current tile, then ONE barrier
// (its implicit vmcnt(0)+lgkmcnt(0) drain makes buffer reuse race-free). The
// prefetch's HBM latency hides under 32 MFMA + cross-wave TLP instead of being
// serialized behind a dedicated stage barrier (the m97-structure ~20% drain stall).
// LDS tiles XOR-swizzled byte^=((row&7)<<4) via inverse-swizzled GLOBAL source
// (rule #21); reads use the same involution. Verified 0 bank conflicts (r2/r3).
template <typename OT, bool LORA>
__global__ __launch_bounds__(256) void mfma_gemm_kernel(const bf16* __restrict__ A, int lda,
        const bf16* __restrict__ W, const float* __restrict__ bias,
        const float* __restrict__ mid, const float* __restrict__ lb,
        OT* __restrict__ C, int M, int N, int KV) {
    __shared__ bf16 As[2][128 * 64];
    __shared__ bf16 Bs[2][128 * 64];
    const int tid = threadIdx.x;
    const int w = tid >> 6, lane = tid & 63;
    const int lr = lane & 15, lg = lane >> 4;
    const int wr = w >> 1, wc = w & 1;

    // bijective XCD-chunk swizzle (nwg % 8 == 0 for both launches)
    const int gx = gridDim.x;
    const int nwg = gx * gridDim.y;
    const int flat = blockIdx.y * gx + blockIdx.x;
    const int cpx = nwg >> 3;
    const int lid = (flat & 7) * cpx + (flat >> 3);
    const int m0 = (lid / gx) * 128, n0 = (lid % gx) * 128;

    f32x4 acc[4][4];
#pragma unroll
    for (int i = 0; i < 4; i++)
#pragma unroll
        for (int j = 0; j < 4; j++) acc[i][j] = (f32x4){0.f, 0.f, 0.f, 0.f};

    // staging source swizzle (rule #21)
    const int brs = lane >> 3;                 // row within 8-row segment
    const int bcsw = ((lane & 7) ^ brs) << 3;  // swizzled col offset, elems (16B chunks)

    const int nt = KV / 64;

    // ---- prologue: stage tile 0 into buffer 0 ----
    {
        const int aOff = 0, wOff = 0;
#pragma unroll
        for (int j = 0; j < 4; j++) {
            int seg = j * 4 + w;
            int row = seg * 8 + brs;
            gload_lds16(A + (size_t)(m0 + row) * lda + aOff + bcsw, &As[0][seg * 512]);
            gload_lds16(W + (size_t)(n0 + row) * 1536 + wOff + bcsw, &Bs[0][seg * 512]);
        }
    }
    __syncthreads();

    int cur = 0;
    for (int t = 0; t < nt; ++t) {
        // ---- issue next-tile prefetch into the other buffer (overlaps compute) ----
        if (t + 1 < nt) {
            const int k0 = (t + 1) * 64;
            const int aOff = (k0 >= 768) ? k0 - 768 : k0;
            const int wOff = (k0 >= 1536) ? k0 - 1536 : k0;
            const int nxt = cur ^ 1;
#pragma unroll
            for (int j = 0; j < 4; j++) {
                int seg = j * 4 + w;
                int row = seg * 8 + brs;
                gload_lds16(A + (size_t)(m0 + row) * lda + aOff + bcsw, &As[nxt][seg * 512]);
                gload_lds16(W + (size_t)(n0 + row) * 1536 + wOff + bcsw, &Bs[nxt][seg * 512]);
            }
        }
        // ---- ds_read fragments of current tile ----
        bf16x8 a[4][2], b[4][2];
#pragma unroll
        for (int mf = 0; mf < 4; mf++) {
            int row = wr * 64 + mf * 16 + lr;
            int sw = (row & 7) << 4;
            a[mf][0] = *(const bf16x8*)((const char*)&As[cur][0] + row * 128 + ((lg * 16) ^ sw));
            a[mf][1] = *(const bf16x8*)((const char*)&As[cur][0] + row * 128 + ((64 + lg * 16) ^ sw));
        }
#pragma unroll
        for (int nf = 0; nf < 4; nf++) {
            int row = wc * 64 + nf * 16 + lr;
            int sw = (row & 7) << 4;
            b[nf][0] = *(const bf16x8*)((const char*)&Bs[cur][0] + row * 128 + ((lg * 16) ^ sw));
            b[nf][1] = *(const bf16x8*)((const char*)&Bs[cur][0] + row * 128 + ((64 + lg * 16) ^ sw));
        }
        // ---- 32 MFMA ----
        __builtin_amdgcn_s_setprio(1);
#pragma unroll
        for (int mf = 0; mf < 4; mf++)
#pragma unroll
            for (int nf = 0; nf < 4; nf++) {
                acc[mf][nf] = __builtin_amdgcn_mfma_f32_16x16x32_bf16(a[mf][0], b[nf][0], acc[mf][nf], 0, 0, 0);
                acc[mf][nf] = __builtin_amdgcn_mfma_f32_16x16x32_bf16(a[mf][1], b[nf][1], acc[mf][nf], 0, 0, 0);
            }
        __builtin_amdgcn_s_setprio(0);
        // ---- single barrier: drains this wave's prefetch (vmcnt) + all lds reads ----
        __syncthreads();
        cur ^= 1;
    }
    // ---- epilogue: bias (+ LoRA), store ----
#pragma unroll
    for (int mf = 0; mf < 4; mf++) {
#pragma unroll
        for (int r = 0; r < 4; r++) {
            int m = m0 + wr * 64 + mf * 16 + lg * 4 + r;
            if (m < M) {
                float mr[8];
                if constexpr (LORA) {
                    float4 u0 = *reinterpret_cast<const float4*>(mid + (size_t)m * 8);
                    float4 u1 = *reinterpret_cast<const float4*>(mid + (size_t)m * 8 + 4);
                    mr[0] = u0.x; mr[1] = u0.y; mr[2] = u0.z; mr[3] = u0.w;
                    mr[4] = u1.x; mr[5] = u1.y; mr[6] = u1.z; mr[7] = u1.w;
                }
#pragma unroll
                for (int nf = 0; nf < 4; nf++) {
                    int n = n0 + wc * 64 + nf * 16 + lr;
                    float v = acc[mf][nf][r] + bias[n];
                    if constexpr (LORA) {
                        const float4 l0 = *reinterpret_cast<const float4*>(lb + (size_t)n * 8);
                        const float4 l1 = *reinterpret_cast<const float4*>(lb + (size_t)n * 8 + 4);
                        v += mr[0] * l0.x + mr[1] * l0.y + mr[2] * l0.z + mr[3] * l0.w
                           + mr[4] * l1.x + mr[5] * l1.y + mr[6] * l1.z + mr[7] * l1.w;
                    }
                    storeC(C + (size_t)m * N + n, v);
                }
            }
        }
    }
}

// ---------------- Fused per-frame attention, MFMA version ----------------
__global__ __launch_bounds__(256) void attn_kernel(const bf16* __restrict__ qkv,
        bf16* __restrict__ ao) {
    __shared__ bf16 Ks[208 * 64];      // [row][64]
    __shared__ bf16 Vt[64 * 208];      // [d][kk]
    __shared__ bf16 Ps[4][16 * 208];   // per-wave [q][kk]
    const int bb = blockIdx.x / NH;
    const int h = blockIdx.x % NH;
    const bf16* base = qkv + (size_t)bb * TP * N3;
    const int tid = threadIdx.x;
    const int w = tid >> 6, lane = tid & 63;
    const int lr = lane & 15, lg = lane >> 4;

    for (int idx = tid; idx < 208 * 16; idx += 256) {
        int row = idx >> 4, d4 = (idx & 15) * 4;
        ushort4 v = make_ushort4(0, 0, 0, 0);
        if (row < TP)
            v = *(const ushort4*)(base + (size_t)row * N3 + EDIM + h * 64 + d4);
        *(ushort4*)((char*)Ks + ((row * 128 + d4 * 2) ^ ((row & 7) << 4))) = v;
    }
    for (int g = w; g < 52; g += 4) {
        int kk0 = g * 4;
        int d = lane;
        const bf16* vb = base + (size_t)kk0 * N3 + 2 * EDIM + h * 64 + d;
        unsigned short t0 = 0, t1 = 0, t2 = 0, t3 = 0;
        if (kk0 + 0 < TP) t0 = *(const unsigned short*)(vb);
        if (kk0 + 1 < TP) t1 = *(const unsigned short*)(vb + N3);
        if (kk0 + 2 < TP) t2 = *(const unsigned short*)(vb + 2 * N3);
        if (kk0 + 3 < TP) t3 = *(const unsigned short*)(vb + 3 * N3);
        ushort4 v; v.x = t0; v.y = t1; v.z = t2; v.w = t3;
        *(ushort4*)((char*)Vt + ((d * 416 + kk0 * 2) ^ ((d & 7) << 4))) = v;
    }
    __syncthreads();

    bf16* Pw = &Ps[w][0];

    for (int qt = w; qt < 13; qt += 4) {
        int q = qt * 16 + lr; if (q > TP - 1) q = TP - 1;
        const bf16* qp = base + (size_t)q * N3 + h * 64 + lg * 8;
        bf16x8 qa0 = *(const bf16x8*)qp;
        bf16x8 qa1 = *(const bf16x8*)(qp + 32);

        f32x4 sf[13];
#pragma unroll
        for (int f = 0; f < 13; f++) {
            int row = f * 16 + lr;
            int swz = (row & 7) << 4;
            bf16x8 kb0 = *(const bf16x8*)((const char*)Ks + ((row * 128 + lg * 16) ^ swz));
            bf16x8 kb1 = *(const bf16x8*)((const char*)Ks + ((row * 128 + 64 + lg * 16) ^ swz));
            f32x4 c = {0.f, 0.f, 0.f, 0.f};
            c = __builtin_amdgcn_mfma_f32_16x16x32_bf16(qa0, kb0, c, 0, 0, 0);
            c = __builtin_amdgcn_mfma_f32_16x16x32_bf16(qa1, kb1, c, 0, 0, 0);
            sf[f] = c;
        }

        float mx[4] = {-1e30f, -1e30f, -1e30f, -1e30f};
#pragma unroll
        for (int f = 0; f < 13; f++) {
#pragma unroll
            for (int r = 0; r < 4; r++) {
                float s = sf[f][r] * SCALE;
                if (f == 12 && lr >= 5) s = -1e30f;
                sf[f][r] = s;
                mx[r] = fmaxf(mx[r], s);
            }
        }
#pragma unroll
        for (int off = 8; off >= 1; off >>= 1) {
#pragma unroll
            for (int r = 0; r < 4; r++) mx[r] = fmaxf(mx[r], __shfl_xor(mx[r], off, 64));
        }
        float lsum[4] = {0.f, 0.f, 0.f, 0.f};
#pragma unroll
        for (int f = 0; f < 13; f++) {
#pragma unroll
            for (int r = 0; r < 4; r++) {
                float e = __expf(sf[f][r] - mx[r]);
                sf[f][r] = e;
                lsum[r] += e;
            }
        }
#pragma unroll
        for (int off = 8; off >= 1; off >>= 1) {
#pragma unroll
            for (int r = 0; r < 4; r++) lsum[r] += __shfl_xor(lsum[r], off, 64);
        }
        float inv[4];
#pragma unroll
        for (int r = 0; r < 4; r++) inv[r] = 1.f / lsum[r];

#pragma unroll
        for (int f = 0; f < 13; f++) {
#pragma unroll
            for (int r = 0; r < 4; r++) {
                int row = lg * 4 + r;
                int col = f * 16 + lr;
                *(bf16*)((char*)Pw + ((row * 416 + col * 2) ^ ((row & 7) << 4))) =
                    __float2bfloat16(sf[f][r]);
            }
        }

        f32x4 of[4];
#pragma unroll
        for (int dt = 0; dt < 4; dt++) of[dt] = (f32x4){0.f, 0.f, 0.f, 0.f};
#pragma unroll
        for (int ks = 0; ks < 7; ks++) {
            int k0 = ks * 32 + lg * 8;
            bool ok = (k0 < 208);
            bf16x8 pa = {0, 0, 0, 0, 0, 0, 0, 0};
            if (ok)
                pa = *(const bf16x8*)((const char*)Pw + ((lr * 416 + k0 * 2) ^ ((lr & 7) << 4)));
#pragma unroll
            for (int dt = 0; dt < 4; dt++) {
                bf16x8 vb = {0, 0, 0, 0, 0, 0, 0, 0};
                if (ok) {
                    int d = dt * 16 + lr;
                    vb = *(const bf16x8*)((const char*)Vt + ((d * 416 + k0 * 2) ^ ((d & 7) << 4)));
                }
                of[dt] = __builtin_amdgcn_mfma_f32_16x16x32_bf16(pa, vb, of[dt], 0, 0, 0);
            }
        }

#pragma unroll
        for (int dt = 0; dt < 4; dt++) {
#pragma unroll
            for (int r = 0; r < 4; r++) {
                int qq = qt * 16 + lg * 4 + r;
                if (qq < TP)
                    ao[((size_t)bb * TP + qq) * EDIM + h * 64 + dt * 16 + lr] =
                        __float2bfloat16(of[dt][r] * inv[r]);
            }
        }
    }
}

// ---------------- Fused cross-frame CLS attention (flash-style online softmax) ----------
__global__ __launch_bounds__(256) void xattn_kernel(const bf16* __restrict__ qkv,
        float* __restrict__ x1p) {
    __shared__ float q1[NF][64];
    __shared__ bf16 Ks[128][64];
    __shared__ bf16 Vs[128][64];
    __shared__ float sc[NF][128];
    __shared__ float Oacc[NF][64];
    __shared__ float mrow[NF], lrow[NF], arow[NF];
    const int b = blockIdx.x / NH, h = blockIdx.x % NH;
    const int tid = threadIdx.x;
    for (int idx = tid; idx < NF * 64; idx += 256) {
        int f = idx >> 6, d = idx & 63;
        q1[f][d] = b2f(qkv[(size_t)((b * NF + f) * TP) * N3 + h * 64 + d]);
        Oacc[f][d] = 0.f;
    }
    if (tid < NF) { mrow[tid] = -1e30f; lrow[tid] = 0.f; }
    __syncthreads();
    const int w = tid >> 6, lane = tid & 63;
    for (int kk0 = 0; kk0 < KALL; kk0 += 128) {
        for (int idx = tid; idx < 128 * 16; idx += 256) {
            int r = idx >> 4, d4 = (idx & 15) * 4;
            int kk = kk0 + r;
            if (kk < KALL) {
                int f = kk / TP, pp = kk - f * TP;
                const bf16* src = qkv + (size_t)((b * NF + f) * TP + pp) * N3 + h * 64 + d4;
                *(ushort4*)&Ks[r][d4] = *(const ushort4*)(src + 768);
                *(ushort4*)&Vs[r][d4] = *(const ushort4*)(src + 1536);
            } else {
                ushort4 z; z.x = z.y = z.z = z.w = 0;
                *(ushort4*)&Ks[r][d4] = z;
                *(ushort4*)&Vs[r][d4] = z;
            }
        }
        __syncthreads();
        for (int idx = tid; idx < NF * 128; idx += 256) {
            int f = idx >> 7, r = idx & 127;
            float s = -1e30f;
            if (kk0 + r < KALL) {
                const bf16* kr = &Ks[r][0];
                float a = 0.f;
#pragma unroll
                for (int d2 = 0; d2 < 32; d2++) {
                    unsigned int u = *reinterpret_cast<const unsigned int*>(kr + 2 * d2);
                    a += q1[f][2 * d2] * __uint_as_float(u << 16);
                    a += q1[f][2 * d2 + 1] * __uint_as_float(u & 0xffff0000u);
                }
                s = a * SCALE;
            }
            sc[f][r] = s;
        }
        __syncthreads();
        for (int qi = 0; qi < 3; qi++) {
            int f = qi * 4 + w;
            float s0 = sc[f][lane], s1v = sc[f][lane + 64];
            float mx = fmaxf(s0, s1v);
#pragma unroll
            for (int off = 32; off >= 1; off >>= 1) mx = fmaxf(mx, __shfl_xor(mx, off, 64));
            float mold = mrow[f];
            float mnew = fmaxf(mold, mx);
            float e0 = __expf(s0 - mnew), e1 = __expf(s1v - mnew);
            float ls = e0 + e1;
#pragma unroll
            for (int off = 32; off >= 1; off >>= 1) ls += __shfl_xor(ls, off, 64);
            sc[f][lane] = e0; sc[f][lane + 64] = e1;
            if (lane == 0) {
                float alpha = __expf(mold - mnew);
                arow[f] = alpha;
                lrow[f] = lrow[f] * alpha + ls;
                mrow[f] = mnew;
            }
        }
        __syncthreads();
        for (int idx = tid; idx < NF * 64; idx += 256) {
            int f = idx >> 6, d = idx & 63;
            float o = Oacc[f][d] * arow[f];
#pragma unroll 4
            for (int r = 0; r < 128; r++)
                o += sc[f][r] * b2f(Vs[r][d]);
            Oacc[f][d] = o;
        }
        __syncthreads();
    }
    for (int idx = tid; idx < NF * 64; idx += 256) {
        int f = idx >> 6, d = idx & 63;
        x1p[(size_t)(b * NF + f) * EDIM + h * 64 + d] = Oacc[f][d] / lrow[f];
    }
}

// ---------------- CLS fixup: out[:,:,0,:] = MLP(out[:,:,0,:]) + x1p @ Wout^T + ob --------
__global__ __launch_bounds__(256) void cls_kernel(float* __restrict__ out,
        const float* __restrict__ x1p, const float* __restrict__ Wout, const float* __restrict__ ob,
        const float* __restrict__ dw, const float* __restrict__ db,
        const float* __restrict__ uw, const float* __restrict__ ub) {
    __shared__ float x0s[EDIM], x1s[EDIM], gs[8];
    const int bfi = blockIdx.x;
    float* row = out + (size_t)bfi * TP * EDIM;  // p = 0 row
    const int tid = threadIdx.x;
    for (int i = tid; i < EDIM; i += 256) {
        x0s[i] = row[i];
        x1s[i] = x1p[(size_t)bfi * EDIM + i];
    }
    __syncthreads();
    {
        int r = tid >> 5, sl = tid & 31;
        float pr = 0.f;
        for (int e = sl; e < EDIM; e += 32) pr += x0s[e] * dw[r * EDIM + e];
#pragma unroll
        for (int off = 16; off >= 1; off >>= 1) pr += __shfl_xor(pr, off, 64);
        if (sl == 0) gs[r] = pr + db[r];
    }
    __syncthreads();
    float act[8];
#pragma unroll
    for (int r = 0; r < 8; r++) { float g = gs[r]; act[r] = g / (1.f + __expf(-1.702f * g)); }
    for (int j = tid; j < EDIM; j += 256) {
        float y = ub[j] + ob[j];
        const float4 u0 = *reinterpret_cast<const float4*>(uw + (size_t)j * 8);
        const float4 u1 = *reinterpret_cast<const float4*>(uw + (size_t)j * 8 + 4);
        y += act[0] * u0.x + act[1] * u0.y + act[2] * u0.z + act[3] * u0.w
           + act[4] * u1.x + act[5] * u1.y + act[6] * u1.z + act[7] * u1.w;
        const float* wr = Wout + (size_t)j * EDIM;
        float s = 0.f;
        for (int e = 0; e < EDIM; e += 4) {
            float4 wv = *reinterpret_cast<const float4*>(wr + e);
            s += x1s[e] * wv.x + x1s[e + 1] * wv.y + x1s[e + 2] * wv.z + x1s[e + 3] * wv.w;
        }
        y += s;
        row[j] = y;
    }
}

extern "C" void kernel_launch(void* const* d_in, const int* in_sizes, int n_in,
                              void* d_out, int out_size, void* d_ws, size_t ws_size,
                              hipStream_t stream) {
    (void)in_sizes; (void)n_in; (void)out_size; (void)ws_size;
    const float* x   = (const float*)d_in[0];
    const float* ipw = (const float*)d_in[1];
    const float* ipb = (const float*)d_in[2];
    const float* opw = (const float*)d_in[3];
    const float* opb = (const float*)d_in[4];
    const float* la  = (const float*)d_in[5];
    const float* lb  = (const float*)d_in[6];
    const float* dw  = (const float*)d_in[7];
    const float* db  = (const float*)d_in[8];
    const float* uw  = (const float*)d_in[9];
    const float* ub  = (const float*)d_in[10];
    float* out = (float*)d_out;   // fp32 output per reference dtype

    // workspace: qkv 174.3 + ao 58.2 + xs 116.4 + W1 7.1 + W2 2.4 + mid 1.2 + x1p 0.6 ≈ 360 MB
    char* wsb = (char*)d_ws;
    bf16* qkv = (bf16*)wsb;                       wsb += (size_t)NT * N3 * sizeof(bf16);
    bf16* ao  = (bf16*)wsb;                       wsb += (size_t)MPAD * EDIM * sizeof(bf16);
    bf16* xs  = (bf16*)wsb;                       wsb += (size_t)MPAD * 1536 * sizeof(bf16);
    bf16* W1  = (bf16*)wsb;                       wsb += (size_t)N3 * 1536 * sizeof(bf16);
    bf16* W2  = (bf16*)wsb;                       wsb += (size_t)EDIM * 1536 * sizeof(bf16);
    float* mid = (float*)wsb;                     wsb += (size_t)NT * 8 * sizeof(float);
    float* x1p = (float*)wsb;                     wsb += (size_t)NB * NF * EDIM * sizeof(float);

    split_w_kernel<<<(N3 * 192 + 255) / 256, 256, 0, stream>>>(ipw, W1, N3);
    split_w_kernel<<<(EDIM * 192 + 255) / 256, 256, 0, stream>>>(opw, W2, EDIM);
    split_w_kernel<<<(NT * 192 + 255) / 256, 256, 0, stream>>>(x, xs, NT);
    lora_mid_kernel<<<NT / 4, 256, 0, stream>>>(x, la, mid);
    // QKV: virtual K = 2304 (hi*Whi + hi*Wlo + lo*Whi)
    mfma_gemm_kernel<bf16, true><<<dim3(N3 / 128, MPAD / 128), 256, 0, stream>>>(
        xs, 1536, W1, ipb, mid, lb, qkv, NT, N3, 2304);
    attn_kernel<<<192 * NH, 256, 0, stream>>>(qkv, ao);
    xattn_kernel<<<NB * NH, 256, 0, stream>>>(qkv, x1p);
    // out-proj: virtual K = 1536 (ao*Whi + ao*Wlo)
    mfma_gemm_kernel<float, false><<<dim3(EDIM / 128, MPAD / 128), 256, 0, stream>>>(
        ao, 768, W2, opb, nullptr, nullptr, out, NT, EDIM, 1536);
    cls_kernel<<<NB * NF, 256, 0, stream>>>(out, x1p, opw, opb, dw, db, uw, ub);
}

// Round 6
// 1514.476 us; speedup vs baseline: 3.1919x; 1.0176x over previous
//
#include <hip/hip_runtime.h>
#include <hip/hip_bf16.h>

typedef __hip_bfloat16 bf16;
typedef __attribute__((ext_vector_type(8))) short bf16x8;   // 8 bf16 = 4 VGPRs (MFMA A/B frag)
typedef __attribute__((ext_vector_type(4))) float f32x4;    // MFMA C/D frag

#define NT   37824   // total tokens = 192*197
#define MPAD 37888   // 148*256 (padded rows for 256-tile GEMM)
#define EDIM 768
#define N3   2304
#define TP   197     // tokens per frame
#define NB   16
#define NF   12
#define NH   12
#define HD   64
#define SCALE 0.125f
#define KALL 2364    // 12*197

__device__ __forceinline__ float bits2f(unsigned short u) {
    unsigned int v = ((unsigned int)u) << 16;
    return __uint_as_float(v);
}
__device__ __forceinline__ float b2f(bf16 v) { return __bfloat162float(v); }

__device__ __forceinline__ unsigned short bhi(float x) {
    union { bf16 b; unsigned short u; } cv; cv.b = __float2bfloat16(x); return cv.u;
}
__device__ __forceinline__ unsigned short blo(float x, unsigned short h) {
    float hf = __uint_as_float(((unsigned int)h) << 16);
    union { bf16 b; unsigned short u; } cv; cv.b = __float2bfloat16(x - hf); return cv.u;
}

__device__ __forceinline__ void storeC(float* p, float v) { *p = v; }
__device__ __forceinline__ void storeC(bf16* p, float v) { *p = __float2bfloat16(v); }

// async global->LDS, 16B per lane; lds dest = wave-uniform base + lane*16
__device__ __forceinline__ void gload_lds16(const bf16* g, bf16* l) {
    __builtin_amdgcn_global_load_lds(
        (const __attribute__((address_space(1))) void*)g,
        (__attribute__((address_space(3))) void*)l,
        16, 0, 0);
}

// ---------------- K1: mid = x @ lora_a^T  (NT x 8), fp32 in ----------------
__global__ __launch_bounds__(256) void lora_mid_kernel(const float* __restrict__ x,
        const float* __restrict__ la, float* __restrict__ mid) {
    int t = blockIdx.x * 4 + (threadIdx.x >> 6);
    int lane = threadIdx.x & 63;
    if (t >= NT) return;
    float acc[8];
#pragma unroll
    for (int r = 0; r < 8; r++) acc[r] = 0.f;
    const float* xr = x + (size_t)t * EDIM;
    for (int e = lane; e < EDIM; e += 64) {
        float xv = xr[e];
#pragma unroll
        for (int r = 0; r < 8; r++) acc[r] += xv * la[r * EDIM + e];
    }
#pragma unroll
    for (int r = 0; r < 8; r++) {
        float v = acc[r];
#pragma unroll
        for (int off = 32; off >= 1; off >>= 1) v += __shfl_xor(v, off, 64);
        if (lane == 0) mid[(size_t)t * 8 + r] = v;
    }
}

// ---- split fp32 rows x 768 -> bf16 [hi | lo] rows x 1536 (used for W and for x) --------
__global__ __launch_bounds__(256) void split_w_kernel(const float* __restrict__ w,
        bf16* __restrict__ o, int rows) {
    int idx = blockIdx.x * 256 + threadIdx.x;
    int total = rows * 192;                        // 768/4 float4-chunks per row
    if (idx >= total) return;
    int r = idx / 192, c = (idx - r * 192) * 4;
    float4 v = *reinterpret_cast<const float4*>(w + (size_t)r * 768 + c);
    ushort4 hi, lo;
    hi.x = bhi(v.x); hi.y = bhi(v.y); hi.z = bhi(v.z); hi.w = bhi(v.w);
    lo.x = blo(v.x, hi.x); lo.y = blo(v.y, hi.y); lo.z = blo(v.z, hi.z); lo.w = blo(v.w, hi.w);
    *(ushort4*)(o + (size_t)r * 1536 + c) = hi;
    *(ushort4*)(o + (size_t)r * 1536 + 768 + c) = lo;
}

// ---------------- MFMA GEMM, 256x256 tile, counted-vmcnt pipeline ----------------
// Virtual-K decomposition (fp32 accuracy from bf16 MFMA):
//   QKV  (KV=2304, A = xs [x_hi | x_lo], lda=1536): x_hi@Whi + x_hi@Wlo + x_lo@Whi
//   proj (KV=1536, A = ao,               lda=768 ): ao@Whi + ao@Wlo
// 8 waves (2M x 4N), per-wave output 128x64, BK=64; LDS = 2 dbuf x (A 32KB + B 32KB)
// = 128 KiB. Schedule per K-tile t (buf[cur] holds t; t+1's 8 loads/wave in flight):
//   P1: ds_read b[4][2]+a(mhalf0)[4][2]; setprio(1); 32 MFMA; setprio(0); s_barrier
//   P2: ds_read a(mhalf1)[4][2];         setprio(1); 32 MFMA; setprio(0); s_barrier
//       (buf[cur] now dead for all waves)
//   issue tile t+2's 8 gload_lds into buf[cur]; s_waitcnt vmcnt(8)  <- counted, not 0:
//       waits only for t+1's loads; t+2's stay in flight across t+1's compute (T4).
//   s_barrier (cross-wave visibility of t+1's LDS writes); cur ^= 1.
// Race-freedom: each wave's vmcnt(8) drains its OWN t+1 loads pre-barrier, so
// post-barrier all waves' t+1 LDS writes are complete; ds_reads are plain loads
// (compiler lgkmcnt before MFMA use, which precedes the phase barrier, which
// precedes re-staging of that buffer). asm "memory" + sched_barrier(0) pin order
// (rule #18). Swizzle: LDS byte^=((row&7)<<4) via inverse-swizzled global source
// (rule #21), read with the same involution. 0 bank conflicts verified r2-r4.
template <typename OT, bool LORA>
__global__ __launch_bounds__(512, 2) void mfma_gemm_kernel(const bf16* __restrict__ A, int lda,
        const bf16* __restrict__ W, const float* __restrict__ bias,
        const float* __restrict__ mid, const float* __restrict__ lb,
        OT* __restrict__ C, int M, int N, int KV) {
    __shared__ bf16 As[2][256 * 64];
    __shared__ bf16 Bs[2][256 * 64];
    const int tid = threadIdx.x;
    const int w = tid >> 6, lane = tid & 63;
    const int lr = lane & 15, lg = lane >> 4;
    const int wr = w >> 2, wc = w & 3;          // 2M x 4N wave grid

    // bijective XCD-chunk swizzle (general form, m204; nwg not necessarily %8==0)
    const int gx = gridDim.x;
    const int nwg = gx * gridDim.y;
    const int flat = blockIdx.y * gx + blockIdx.x;
    const int xcd = flat & 7, loc = flat >> 3;
    const int q = nwg >> 3, rmd = nwg & 7;
    const int lid = (xcd < rmd ? xcd * (q + 1) : rmd * (q + 1) + (xcd - rmd) * q) + loc;
    const int m0 = (lid / gx) * 256, n0 = (lid % gx) * 256;

    f32x4 acc[8][4];
#pragma unroll
    for (int i = 0; i < 8; i++)
#pragma unroll
        for (int j = 0; j < 4; j++) acc[i][j] = (f32x4){0.f, 0.f, 0.f, 0.f};

    // staging source swizzle (rule #21): lane covers row (lane>>3) of an 8-row seg,
    // col chunk ((lane&7)^(lane>>3)); linear LDS dest then holds the XOR layout.
    const int brs = lane >> 3;
    const int bcsw = ((lane & 7) ^ brs) << 3;

    // wave w stages rows w*32 .. w*32+31 of both A and B tiles (4 x 1KB segs each)
    auto STAGE = [&](bf16* dA, bf16* dB, int aO, int wO) {
#pragma unroll
        for (int j = 0; j < 4; ++j) {
            int rA = w * 32 + j * 8;
            gload_lds16(A + (size_t)(m0 + rA + brs) * lda + aO + bcsw, dA + rA * 64);
            gload_lds16(W + (size_t)(n0 + rA + brs) * 1536 + wO + bcsw, dB + rA * 64);
        }
    };

    const int nt = KV / 64;
    // ---- prologue: stage tiles 0,1; wait tile 0 (8 newest = tile 1 stay in flight) ----
    STAGE(&As[0][0], &Bs[0][0], 0, 0);
    {
        const int k1 = 64;
        STAGE(&As[1][0], &Bs[1][0], (k1 >= 768) ? k1 - 768 : k1, k1);
    }
    asm volatile("s_waitcnt vmcnt(8)" ::: "memory");
    __builtin_amdgcn_sched_barrier(0);
    __builtin_amdgcn_s_barrier();
    __builtin_amdgcn_sched_barrier(0);

    int cur = 0;
    for (int t = 0; t < nt; ++t) {
        const char* pA = (const char*)&As[cur][0];
        const char* pB = (const char*)&Bs[cur][0];
        bf16x8 a[4][2], b[4][2];
        // ---- B frags (all 4 nf, live across both phases) ----
#pragma unroll
        for (int nf = 0; nf < 4; nf++) {
            int row = wc * 64 + nf * 16 + lr;
            int sw = (row & 7) << 4;
            b[nf][0] = *(const bf16x8*)(pB + row * 128 + ((lg * 16) ^ sw));
            b[nf][1] = *(const bf16x8*)(pB + row * 128 + ((64 + lg * 16) ^ sw));
        }
        // ---- phase 1: m-half 0 ----
#pragma unroll
        for (int mf = 0; mf < 4; mf++) {
            int row = wr * 128 + mf * 16 + lr;
            int sw = (row & 7) << 4;
            a[mf][0] = *(const bf16x8*)(pA + row * 128 + ((lg * 16) ^ sw));
            a[mf][1] = *(const bf16x8*)(pA + row * 128 + ((64 + lg * 16) ^ sw));
        }
        __builtin_amdgcn_s_setprio(1);
#pragma unroll
        for (int mf = 0; mf < 4; mf++)
#pragma unroll
            for (int nf = 0; nf < 4; nf++) {
                acc[mf][nf] = __builtin_amdgcn_mfma_f32_16x16x32_bf16(a[mf][0], b[nf][0], acc[mf][nf], 0, 0, 0);
                acc[mf][nf] = __builtin_amdgcn_mfma_f32_16x16x32_bf16(a[mf][1], b[nf][1], acc[mf][nf], 0, 0, 0);
            }
        __builtin_amdgcn_s_setprio(0);
        __builtin_amdgcn_sched_barrier(0);
        __builtin_amdgcn_s_barrier();
        __builtin_amdgcn_sched_barrier(0);
        // ---- phase 2: m-half 1 (reuse a regs) ----
#pragma unroll
        for (int mf = 0; mf < 4; mf++) {
            int row = wr * 128 + 64 + mf * 16 + lr;
            int sw = (row & 7) << 4;
            a[mf][0] = *(const bf16x8*)(pA + row * 128 + ((lg * 16) ^ sw));
            a[mf][1] = *(const bf16x8*)(pA + row * 128 + ((64 + lg * 16) ^ sw));
        }
        __builtin_amdgcn_s_setprio(1);
#pragma unroll
        for (int mf = 0; mf < 4; mf++)
#pragma unroll
            for (int nf = 0; nf < 4; nf++) {
                acc[4 + mf][nf] = __builtin_amdgcn_mfma_f32_16x16x32_bf16(a[mf][0], b[nf][0], acc[4 + mf][nf], 0, 0, 0);
                acc[4 + mf][nf] = __builtin_amdgcn_mfma_f32_16x16x32_bf16(a[mf][1], b[nf][1], acc[4 + mf][nf], 0, 0, 0);
            }
        __builtin_amdgcn_s_setprio(0);
        __builtin_amdgcn_sched_barrier(0);
        __builtin_amdgcn_s_barrier();            // all waves done reading buf[cur]
        __builtin_amdgcn_sched_barrier(0);
        // ---- stage tile t+2 into freed buffer; counted wait for tile t+1 ----
        if (t + 2 < nt) {
            const int k2 = (t + 2) * 64;
            STAGE(&As[cur][0], &Bs[cur][0],
                  (k2 >= 768) ? k2 - 768 : k2,
                  (k2 >= 1536) ? k2 - 1536 : k2);
            asm volatile("s_waitcnt vmcnt(8)" ::: "memory");
        } else {
            asm volatile("s_waitcnt vmcnt(0)" ::: "memory");
        }
        __builtin_amdgcn_sched_barrier(0);
        __builtin_amdgcn_s_barrier();            // t+1's LDS writes visible to all
        __builtin_amdgcn_sched_barrier(0);
        cur ^= 1;
    }
    // ---- epilogue: bias (+ LoRA), store ----
#pragma unroll
    for (int mf = 0; mf < 8; mf++) {
#pragma unroll
        for (int r = 0; r < 4; r++) {
            int m = m0 + wr * 128 + mf * 16 + lg * 4 + r;
            if (m < M) {
                float mr[8];
                if constexpr (LORA) {
                    float4 u0 = *reinterpret_cast<const float4*>(mid + (size_t)m * 8);
                    float4 u1 = *reinterpret_cast<const float4*>(mid + (size_t)m * 8 + 4);
                    mr[0] = u0.x; mr[1] = u0.y; mr[2] = u0.z; mr[3] = u0.w;
                    mr[4] = u1.x; mr[5] = u1.y; mr[6] = u1.z; mr[7] = u1.w;
                }
#pragma unroll
                for (int nf = 0; nf < 4; nf++) {
                    int n = n0 + wc * 64 + nf * 16 + lr;
                    float v = acc[mf][nf][r] + bias[n];
                    if constexpr (LORA) {
                        const float4 l0 = *reinterpret_cast<const float4*>(lb + (size_t)n * 8);
                        const float4 l1 = *reinterpret_cast<const float4*>(lb + (size_t)n * 8 + 4);
                        v += mr[0] * l0.x + mr[1] * l0.y + mr[2] * l0.z + mr[3] * l0.w
                           + mr[4] * l1.x + mr[5] * l1.y + mr[6] * l1.z + mr[7] * l1.w;
                    }
                    storeC(C + (size_t)m * N + n, v);
                }
            }
        }
    }
}

// ---------------- Fused per-frame attention, MFMA version ----------------
__global__ __launch_bounds__(256) void attn_kernel(const bf16* __restrict__ qkv,
        bf16* __restrict__ ao) {
    __shared__ bf16 Ks[208 * 64];      // [row][64]
    __shared__ bf16 Vt[64 * 208];      // [d][kk]
    __shared__ bf16 Ps[4][16 * 208];   // per-wave [q][kk]
    const int bb = blockIdx.x / NH;
    const int h = blockIdx.x % NH;
    const bf16* base = qkv + (size_t)bb * TP * N3;
    const int tid = threadIdx.x;
    const int w = tid >> 6, lane = tid & 63;
    const int lr = lane & 15, lg = lane >> 4;

    for (int idx = tid; idx < 208 * 16; idx += 256) {
        int row = idx >> 4, d4 = (idx & 15) * 4;
        ushort4 v = make_ushort4(0, 0, 0, 0);
        if (row < TP)
            v = *(const ushort4*)(base + (size_t)row * N3 + EDIM + h * 64 + d4);
        *(ushort4*)((char*)Ks + ((row * 128 + d4 * 2) ^ ((row & 7) << 4))) = v;
    }
    for (int g = w; g < 52; g += 4) {
        int kk0 = g * 4;
        int d = lane;
        const bf16* vb = base + (size_t)kk0 * N3 + 2 * EDIM + h * 64 + d;
        unsigned short t0 = 0, t1 = 0, t2 = 0, t3 = 0;
        if (kk0 + 0 < TP) t0 = *(const unsigned short*)(vb);
        if (kk0 + 1 < TP) t1 = *(const unsigned short*)(vb + N3);
        if (kk0 + 2 < TP) t2 = *(const unsigned short*)(vb + 2 * N3);
        if (kk0 + 3 < TP) t3 = *(const unsigned short*)(vb + 3 * N3);
        ushort4 v; v.x = t0; v.y = t1; v.z = t2; v.w = t3;
        *(ushort4*)((char*)Vt + ((d * 416 + kk0 * 2) ^ ((d & 7) << 4))) = v;
    }
    __syncthreads();

    bf16* Pw = &Ps[w][0];

    for (int qt = w; qt < 13; qt += 4) {
        int q = qt * 16 + lr; if (q > TP - 1) q = TP - 1;
        const bf16* qp = base + (size_t)q * N3 + h * 64 + lg * 8;
        bf16x8 qa0 = *(const bf16x8*)qp;
        bf16x8 qa1 = *(const bf16x8*)(qp + 32);

        f32x4 sf[13];
#pragma unroll
        for (int f = 0; f < 13; f++) {
            int row = f * 16 + lr;
            int swz = (row & 7) << 4;
            bf16x8 kb0 = *(const bf16x8*)((const char*)Ks + ((row * 128 + lg * 16) ^ swz));
            bf16x8 kb1 = *(const bf16x8*)((const char*)Ks + ((row * 128 + 64 + lg * 16) ^ swz));
            f32x4 c = {0.f, 0.f, 0.f, 0.f};
            c = __builtin_amdgcn_mfma_f32_16x16x32_bf16(qa0, kb0, c, 0, 0, 0);
            c = __builtin_amdgcn_mfma_f32_16x16x32_bf16(qa1, kb1, c, 0, 0, 0);
            sf[f] = c;
        }

        float mx[4] = {-1e30f, -1e30f, -1e30f, -1e30f};
#pragma unroll
        for (int f = 0; f < 13; f++) {
#pragma unroll
            for (int r = 0; r < 4; r++) {
                float s = sf[f][r] * SCALE;
                if (f == 12 && lr >= 5) s = -1e30f;
                sf[f][r] = s;
                mx[r] = fmaxf(mx[r], s);
            }
        }
#pragma unroll
        for (int off = 8; off >= 1; off >>= 1) {
#pragma unroll
            for (int r = 0; r < 4; r++) mx[r] = fmaxf(mx[r], __shfl_xor(mx[r], off, 64));
        }
        float lsum[4] = {0.f, 0.f, 0.f, 0.f};
#pragma unroll
        for (int f = 0; f < 13; f++) {
#pragma unroll
            for (int r = 0; r < 4; r++) {
                float e = __expf(sf[f][r] - mx[r]);
                sf[f][r] = e;
                lsum[r] += e;
            }
        }
#pragma unroll
        for (int off = 8; off >= 1; off >>= 1) {
#pragma unroll
            for (int r = 0; r < 4; r++) lsum[r] += __shfl_xor(lsum[r], off, 64);
        }
        float inv[4];
#pragma unroll
        for (int r = 0; r < 4; r++) inv[r] = 1.f / lsum[r];

#pragma unroll
        for (int f = 0; f < 13; f++) {
#pragma unroll
            for (int r = 0; r < 4; r++) {
                int row = lg * 4 + r;
                int col = f * 16 + lr;
                *(bf16*)((char*)Pw + ((row * 416 + col * 2) ^ ((row & 7) << 4))) =
                    __float2bfloat16(sf[f][r]);
            }
        }

        f32x4 of[4];
#pragma unroll
        for (int dt = 0; dt < 4; dt++) of[dt] = (f32x4){0.f, 0.f, 0.f, 0.f};
#pragma unroll
        for (int ks = 0; ks < 7; ks++) {
            int k0 = ks * 32 + lg * 8;
            bool ok = (k0 < 208);
            bf16x8 pa = {0, 0, 0, 0, 0, 0, 0, 0};
            if (ok)
                pa = *(const bf16x8*)((const char*)Pw + ((lr * 416 + k0 * 2) ^ ((lr & 7) << 4)));
#pragma unroll
            for (int dt = 0; dt < 4; dt++) {
                bf16x8 vb = {0, 0, 0, 0, 0, 0, 0, 0};
                if (ok) {
                    int d = dt * 16 + lr;
                    vb = *(const bf16x8*)((const char*)Vt + ((d * 416 + k0 * 2) ^ ((d & 7) << 4)));
                }
                of[dt] = __builtin_amdgcn_mfma_f32_16x16x32_bf16(pa, vb, of[dt], 0, 0, 0);
            }
        }

#pragma unroll
        for (int dt = 0; dt < 4; dt++) {
#pragma unroll
            for (int r = 0; r < 4; r++) {
                int qq = qt * 16 + lg * 4 + r;
                if (qq < TP)
                    ao[((size_t)bb * TP + qq) * EDIM + h * 64 + dt * 16 + lr] =
                        __float2bfloat16(of[dt][r] * inv[r]);
            }
        }
    }
}

// ---------------- Fused cross-frame CLS attention (flash-style online softmax) ----------
__global__ __launch_bounds__(256) void xattn_kernel(const bf16* __restrict__ qkv,
        float* __restrict__ x1p) {
    __shared__ float q1[NF][64];
    __shared__ bf16 Ks[128][64];
    __shared__ bf16 Vs[128][64];
    __shared__ float sc[NF][128];
    __shared__ float Oacc[NF][64];
    __shared__ float mrow[NF], lrow[NF], arow[NF];
    const int b = blockIdx.x / NH, h = blockIdx.x % NH;
    const int tid = threadIdx.x;
    for (int idx = tid; idx < NF * 64; idx += 256) {
        int f = idx >> 6, d = idx & 63;
        q1[f][d] = b2f(qkv[(size_t)((b * NF + f) * TP) * N3 + h * 64 + d]);
        Oacc[f][d] = 0.f;
    }
    if (tid < NF) { mrow[tid] = -1e30f; lrow[tid] = 0.f; }
    __syncthreads();
    const int w = tid >> 6, lane = tid & 63;
    for (int kk0 = 0; kk0 < KALL; kk0 += 128) {
        for (int idx = tid; idx < 128 * 16; idx += 256) {
            int r = idx >> 4, d4 = (idx & 15) * 4;
            int kk = kk0 + r;
            if (kk < KALL) {
                int f = kk / TP, pp = kk - f * TP;
                const bf16* src = qkv + (size_t)((b * NF + f) * TP + pp) * N3 + h * 64 + d4;
                *(ushort4*)&Ks[r][d4] = *(const ushort4*)(src + 768);
                *(ushort4*)&Vs[r][d4] = *(const ushort4*)(src + 1536);
            } else {
                ushort4 z; z.x = z.y = z.z = z.w = 0;
                *(ushort4*)&Ks[r][d4] = z;
                *(ushort4*)&Vs[r][d4] = z;
            }
        }
        __syncthreads();
        for (int idx = tid; idx < NF * 128; idx += 256) {
            int f = idx >> 7, r = idx & 127;
            float s = -1e30f;
            if (kk0 + r < KALL) {
                const bf16* kr = &Ks[r][0];
                float a = 0.f;
#pragma unroll
                for (int d2 = 0; d2 < 32; d2++) {
                    unsigned int u = *reinterpret_cast<const unsigned int*>(kr + 2 * d2);
                    a += q1[f][2 * d2] * __uint_as_float(u << 16);
                    a += q1[f][2 * d2 + 1] * __uint_as_float(u & 0xffff0000u);
                }
                s = a * SCALE;
            }
            sc[f][r] = s;
        }
        __syncthreads();
        for (int qi = 0; qi < 3; qi++) {
            int f = qi * 4 + w;
            float s0 = sc[f][lane], s1v = sc[f][lane + 64];
            float mx = fmaxf(s0, s1v);
#pragma unroll
            for (int off = 32; off >= 1; off >>= 1) mx = fmaxf(mx, __shfl_xor(mx, off, 64));
            float mold = mrow[f];
            float mnew = fmaxf(mold, mx);
            float e0 = __expf(s0 - mnew), e1 = __expf(s1v - mnew);
            float ls = e0 + e1;
#pragma unroll
            for (int off = 32; off >= 1; off >>= 1) ls += __shfl_xor(ls, off, 64);
            sc[f][lane] = e0; sc[f][lane + 64] = e1;
            if (lane == 0) {
                float alpha = __expf(mold - mnew);
                arow[f] = alpha;
                lrow[f] = lrow[f] * alpha + ls;
                mrow[f] = mnew;
            }
        }
        __syncthreads();
        for (int idx = tid; idx < NF * 64; idx += 256) {
            int f = idx >> 6, d = idx & 63;
            float o = Oacc[f][d] * arow[f];
#pragma unroll 4
            for (int r = 0; r < 128; r++)
                o += sc[f][r] * b2f(Vs[r][d]);
            Oacc[f][d] = o;
        }
        __syncthreads();
    }
    for (int idx = tid; idx < NF * 64; idx += 256) {
        int f = idx >> 6, d = idx & 63;
        x1p[(size_t)(b * NF + f) * EDIM + h * 64 + d] = Oacc[f][d] / lrow[f];
    }
}

// ---------------- CLS fixup: out[:,:,0,:] = MLP(out[:,:,0,:]) + x1p @ Wout^T + ob --------
__global__ __launch_bounds__(256) void cls_kernel(float* __restrict__ out,
        const float* __restrict__ x1p, const float* __restrict__ Wout, const float* __restrict__ ob,
        const float* __restrict__ dw, const float* __restrict__ db,
        const float* __restrict__ uw, const float* __restrict__ ub) {
    __shared__ float x0s[EDIM], x1s[EDIM], gs[8];
    const int bfi = blockIdx.x;
    float* row = out + (size_t)bfi * TP * EDIM;  // p = 0 row
    const int tid = threadIdx.x;
    for (int i = tid; i < EDIM; i += 256) {
        x0s[i] = row[i];
        x1s[i] = x1p[(size_t)bfi * EDIM + i];
    }
    __syncthreads();
    {
        int r = tid >> 5, sl = tid & 31;
        float pr = 0.f;
        for (int e = sl; e < EDIM; e += 32) pr += x0s[e] * dw[r * EDIM + e];
#pragma unroll
        for (int off = 16; off >= 1; off >>= 1) pr += __shfl_xor(pr, off, 64);
        if (sl == 0) gs[r] = pr + db[r];
    }
    __syncthreads();
    float act[8];
#pragma unroll
    for (int r = 0; r < 8; r++) { float g = gs[r]; act[r] = g / (1.f + __expf(-1.702f * g)); }
    for (int j = tid; j < EDIM; j += 256) {
        float y = ub[j] + ob[j];
        const float4 u0 = *reinterpret_cast<const float4*>(uw + (size_t)j * 8);
        const float4 u1 = *reinterpret_cast<const float4*>(uw + (size_t)j * 8 + 4);
        y += act[0] * u0.x + act[1] * u0.y + act[2] * u0.z + act[3] * u0.w
           + act[4] * u1.x + act[5] * u1.y + act[6] * u1.z + act[7] * u1.w;
        const float* wr = Wout + (size_t)j * EDIM;
        float s = 0.f;
        for (int e = 0; e < EDIM; e += 4) {
            float4 wv = *reinterpret_cast<const float4*>(wr + e);
            s += x1s[e] * wv.x + x1s[e + 1] * wv.y + x1s[e + 2] * wv.z + x1s[e + 3] * wv.w;
        }
        y += s;
        row[j] = y;
    }
}

extern "C" void kernel_launch(void* const* d_in, const int* in_sizes, int n_in,
                              void* d_out, int out_size, void* d_ws, size_t ws_size,
                              hipStream_t stream) {
    (void)in_sizes; (void)n_in; (void)out_size; (void)ws_size;
    const float* x   = (const float*)d_in[0];
    const float* ipw = (const float*)d_in[1];
    const float* ipb = (const float*)d_in[2];
    const float* opw = (const float*)d_in[3];
    const float* opb = (const float*)d_in[4];
    const float* la  = (const float*)d_in[5];
    const float* lb  = (const float*)d_in[6];
    const float* dw  = (const float*)d_in[7];
    const float* db  = (const float*)d_in[8];
    const float* uw  = (const float*)d_in[9];
    const float* ub  = (const float*)d_in[10];
    float* out = (float*)d_out;   // fp32 output per reference dtype

    // workspace: qkv 174.3 + ao 58.2 + xs 116.4 + W1 7.1 + W2 2.4 + mid 1.2 + x1p 0.6 ≈ 360 MB
    char* wsb = (char*)d_ws;
    bf16* qkv = (bf16*)wsb;                       wsb += (size_t)NT * N3 * sizeof(bf16);
    bf16* ao  = (bf16*)wsb;                       wsb += (size_t)MPAD * EDIM * sizeof(bf16);
    bf16* xs  = (bf16*)wsb;                       wsb += (size_t)MPAD * 1536 * sizeof(bf16);
    bf16* W1  = (bf16*)wsb;                       wsb += (size_t)N3 * 1536 * sizeof(bf16);
    bf16* W2  = (bf16*)wsb;                       wsb += (size_t)EDIM * 1536 * sizeof(bf16);
    float* mid = (float*)wsb;                     wsb += (size_t)NT * 8 * sizeof(float);
    float* x1p = (float*)wsb;                     wsb += (size_t)NB * NF * EDIM * sizeof(float);

    split_w_kernel<<<(N3 * 192 + 255) / 256, 256, 0, stream>>>(ipw, W1, N3);
    split_w_kernel<<<(EDIM * 192 + 255) / 256, 256, 0, stream>>>(opw, W2, EDIM);
    split_w_kernel<<<(NT * 192 + 255) / 256, 256, 0, stream>>>(x, xs, NT);
    lora_mid_kernel<<<NT / 4, 256, 0, stream>>>(x, la, mid);
    // QKV: virtual K = 2304 (hi*Whi + hi*Wlo + lo*Whi)
    mfma_gemm_kernel<bf16, true><<<dim3(N3 / 256, MPAD / 256), 512, 0, stream>>>(
        xs, 1536, W1, ipb, mid, lb, qkv, NT, N3, 2304);
    attn_kernel<<<192 * NH, 256, 0, stream>>>(qkv, ao);
    xattn_kernel<<<NB * NH, 256, 0, stream>>>(qkv, x1p);
    // out-proj: virtual K = 1536 (ao*Whi + ao*Wlo)
    mfma_gemm_kernel<float, false><<<dim3(EDIM / 256, MPAD / 256), 512, 0, stream>>>(
        ao, 768, W2, opb, nullptr, nullptr, out, NT, EDIM, 1536);
    cls_kernel<<<NB * NF, 256, 0, stream>>>(out, x1p, opw, opb, dw, db, uw, ub);
}

// Round 7
// 1456.129 us; speedup vs baseline: 3.3198x; 1.0401x over previous
//
#include <hip/hip_runtime.h>
#include <hip/hip_bf16.h>

typedef __hip_bfloat16 bf16;
typedef __attribute__((ext_vector_type(8))) short bf16x8;   // 8 bf16 = 4 VGPRs (MFMA A/B frag)
typedef __attribute__((ext_vector_type(4))) float f32x4;    // MFMA C/D frag

#define NT   37824   // total tokens = 192*197
#define MPAD 37888   // 148*256 (padded rows for 256-tile GEMM)
#define EDIM 768
#define N3   2304
#define TP   197     // tokens per frame
#define NB   16
#define NF   12
#define NH   12
#define HD   64
#define SCALE 0.125f
#define KALL 2364    // 12*197

__device__ __forceinline__ float bits2f(unsigned short u) {
    unsigned int v = ((unsigned int)u) << 16;
    return __uint_as_float(v);
}
__device__ __forceinline__ float b2f(bf16 v) { return __bfloat162float(v); }

__device__ __forceinline__ unsigned short bhi(float x) {
    union { bf16 b; unsigned short u; } cv; cv.b = __float2bfloat16(x); return cv.u;
}
__device__ __forceinline__ unsigned short blo(float x, unsigned short h) {
    float hf = __uint_as_float(((unsigned int)h) << 16);
    union { bf16 b; unsigned short u; } cv; cv.b = __float2bfloat16(x - hf); return cv.u;
}

__device__ __forceinline__ void storeC(float* p, float v) { *p = v; }
__device__ __forceinline__ void storeC(bf16* p, float v) { *p = __float2bfloat16(v); }

// async global->LDS, 16B per lane; lds dest = wave-uniform base + lane*16
__device__ __forceinline__ void gload_lds16(const bf16* g, bf16* l) {
    __builtin_amdgcn_global_load_lds(
        (const __attribute__((address_space(1))) void*)g,
        (__attribute__((address_space(3))) void*)l,
        16, 0, 0);
}

// ---------------- K1: mid = x @ lora_a^T  (NT x 8), fp32 in ----------------
__global__ __launch_bounds__(256) void lora_mid_kernel(const float* __restrict__ x,
        const float* __restrict__ la, float* __restrict__ mid) {
    int t = blockIdx.x * 4 + (threadIdx.x >> 6);
    int lane = threadIdx.x & 63;
    if (t >= NT) return;
    float acc[8];
#pragma unroll
    for (int r = 0; r < 8; r++) acc[r] = 0.f;
    const float* xr = x + (size_t)t * EDIM;
    for (int e = lane; e < EDIM; e += 64) {
        float xv = xr[e];
#pragma unroll
        for (int r = 0; r < 8; r++) acc[r] += xv * la[r * EDIM + e];
    }
#pragma unroll
    for (int r = 0; r < 8; r++) {
        float v = acc[r];
#pragma unroll
        for (int off = 32; off >= 1; off >>= 1) v += __shfl_xor(v, off, 64);
        if (lane == 0) mid[(size_t)t * 8 + r] = v;
    }
}

// ---- split fp32 rows x 768 -> bf16 [hi | lo] rows x 1536 (used for W and for x) --------
__global__ __launch_bounds__(256) void split_w_kernel(const float* __restrict__ w,
        bf16* __restrict__ o, int rows) {
    int idx = blockIdx.x * 256 + threadIdx.x;
    int total = rows * 192;                        // 768/4 float4-chunks per row
    if (idx >= total) return;
    int r = idx / 192, c = (idx - r * 192) * 4;
    float4 v = *reinterpret_cast<const float4*>(w + (size_t)r * 768 + c);
    ushort4 hi, lo;
    hi.x = bhi(v.x); hi.y = bhi(v.y); hi.z = bhi(v.z); hi.w = bhi(v.w);
    lo.x = blo(v.x, hi.x); lo.y = blo(v.y, hi.y); lo.z = blo(v.z, hi.z); lo.w = blo(v.w, hi.w);
    *(ushort4*)(o + (size_t)r * 1536 + c) = hi;
    *(ushort4*)(o + (size_t)r * 1536 + 768 + c) = lo;
}

// ---------------- MFMA GEMM, 256x256 tile, fine-interleaved counted-vmcnt pipeline ------
// Virtual-K decomposition (fp32 accuracy from bf16 MFMA):
//   QKV  (KV=2304, A = xs [x_hi | x_lo], lda=1536): x_hi@Whi + x_hi@Wlo + x_lo@Whi
//   proj (KV=1536, A = ao,               lda=768 ): ao@Whi + ao@Wlo
// 8 waves (2M x 4N), per-wave output 128x64, BK=64; LDS = 128 KiB (2x dbuf).
// K-loop = 4 quadrant clusters with NO internal barriers (m196: the fine
// ds_read||stage||MFMA interleave is the lever; compiler pipelines the 24 plain
// ds_reads with counted lgkmcnt across clusters):
//   A: read a(mh0)+b0; 16 MFMA(a*b0 -> acc[0-3][0-1])
//   B: read b1;        16 MFMA(a*b1 -> acc[0-3][2-3])
//   C: read a(mh1) (WAR on a[] keeps order); 16 MFMA(a*b1 -> acc[4-7][2-3])
//   bar1  (every read was consumed by an MFMA before this -> lgkm drained)
//   STAGE tile t+2 into freed buf; sched_barrier
//   D: 16 MFMA(a*b0 -> acc[4-7][0-1])  <- registers only, overlaps load flight
//   vmcnt(8) (counted: waits t+1 only, t+2 stays in flight); bar2; cur^=1
// Swizzle: LDS byte^=((row&7)<<4) via inverse-swizzled global source (rule #21),
// read with the same involution. 0 bank conflicts verified r2-r6.
template <typename OT, bool LORA>
__global__ __launch_bounds__(512, 2) void mfma_gemm_kernel(const bf16* __restrict__ A, int lda,
        const bf16* __restrict__ W, const float* __restrict__ bias,
        const float* __restrict__ mid, const float* __restrict__ lb,
        OT* __restrict__ C, int M, int N, int KV) {
    __shared__ bf16 As[2][256 * 64];
    __shared__ bf16 Bs[2][256 * 64];
    const int tid = threadIdx.x;
    const int w = tid >> 6, lane = tid & 63;
    const int lr = lane & 15, lg = lane >> 4;
    const int wr = w >> 2, wc = w & 3;          // 2M x 4N wave grid

    // bijective XCD-chunk swizzle (general form, m204)
    const int gx = gridDim.x;
    const int nwg = gx * gridDim.y;
    const int flat = blockIdx.y * gx + blockIdx.x;
    const int xcd = flat & 7, loc = flat >> 3;
    const int q = nwg >> 3, rmd = nwg & 7;
    const int lid = (xcd < rmd ? xcd * (q + 1) : rmd * (q + 1) + (xcd - rmd) * q) + loc;
    const int m0 = (lid / gx) * 256, n0 = (lid % gx) * 256;

    f32x4 acc[8][4];
#pragma unroll
    for (int i = 0; i < 8; i++)
#pragma unroll
        for (int j = 0; j < 4; j++) acc[i][j] = (f32x4){0.f, 0.f, 0.f, 0.f};

    // staging source swizzle (rule #21)
    const int brs = lane >> 3;
    const int bcsw = ((lane & 7) ^ brs) << 3;

    // wave w stages rows w*32 .. w*32+31 of both A and B tiles (4 x 1KB segs each)
    auto STAGE = [&](bf16* dA, bf16* dB, int aO, int wO) {
#pragma unroll
        for (int j = 0; j < 4; ++j) {
            int rA = w * 32 + j * 8;
            gload_lds16(A + (size_t)(m0 + rA + brs) * lda + aO + bcsw, dA + rA * 64);
            gload_lds16(W + (size_t)(n0 + rA + brs) * 1536 + wO + bcsw, dB + rA * 64);
        }
    };

    const int nt = KV / 64;
    // ---- prologue: stage tiles 0,1; wait tile 0 (tile 1's 8 stay in flight) ----
    STAGE(&As[0][0], &Bs[0][0], 0, 0);
    {
        const int k1 = 64;
        STAGE(&As[1][0], &Bs[1][0], (k1 >= 768) ? k1 - 768 : k1, k1);
    }
    asm volatile("s_waitcnt vmcnt(8)" ::: "memory");
    __builtin_amdgcn_sched_barrier(0);
    __builtin_amdgcn_s_barrier();
    __builtin_amdgcn_sched_barrier(0);

    int cur = 0;
    for (int t = 0; t < nt; ++t) {
        const char* pA = (const char*)&As[cur][0];
        const char* pB = (const char*)&Bs[cur][0];
        bf16x8 a[4][2], b0[2][2], b1[2][2];
        // ---- cluster A: a(m-half0) + b0 (n-frags 0-1) ----
#pragma unroll
        for (int mf = 0; mf < 4; mf++) {
            int row = wr * 128 + mf * 16 + lr;
            int sw = (row & 7) << 4;
            a[mf][0] = *(const bf16x8*)(pA + row * 128 + ((lg * 16) ^ sw));
            a[mf][1] = *(const bf16x8*)(pA + row * 128 + ((64 + lg * 16) ^ sw));
        }
#pragma unroll
        for (int nf = 0; nf < 2; nf++) {
            int row = wc * 64 + nf * 16 + lr;
            int sw = (row & 7) << 4;
            b0[nf][0] = *(const bf16x8*)(pB + row * 128 + ((lg * 16) ^ sw));
            b0[nf][1] = *(const bf16x8*)(pB + row * 128 + ((64 + lg * 16) ^ sw));
        }
        __builtin_amdgcn_s_setprio(1);
#pragma unroll
        for (int mf = 0; mf < 4; mf++)
#pragma unroll
            for (int nf = 0; nf < 2; nf++) {
                acc[mf][nf] = __builtin_amdgcn_mfma_f32_16x16x32_bf16(a[mf][0], b0[nf][0], acc[mf][nf], 0, 0, 0);
                acc[mf][nf] = __builtin_amdgcn_mfma_f32_16x16x32_bf16(a[mf][1], b0[nf][1], acc[mf][nf], 0, 0, 0);
            }
        __builtin_amdgcn_s_setprio(0);
        // ---- cluster B: b1 (n-frags 2-3); a * b1 ----
#pragma unroll
        for (int nf = 0; nf < 2; nf++) {
            int row = wc * 64 + (nf + 2) * 16 + lr;
            int sw = (row & 7) << 4;
            b1[nf][0] = *(const bf16x8*)(pB + row * 128 + ((lg * 16) ^ sw));
            b1[nf][1] = *(const bf16x8*)(pB + row * 128 + ((64 + lg * 16) ^ sw));
        }
        __builtin_amdgcn_s_setprio(1);
#pragma unroll
        for (int mf = 0; mf < 4; mf++)
#pragma unroll
            for (int nf = 0; nf < 2; nf++) {
                acc[mf][nf + 2] = __builtin_amdgcn_mfma_f32_16x16x32_bf16(a[mf][0], b1[nf][0], acc[mf][nf + 2], 0, 0, 0);
                acc[mf][nf + 2] = __builtin_amdgcn_mfma_f32_16x16x32_bf16(a[mf][1], b1[nf][1], acc[mf][nf + 2], 0, 0, 0);
            }
        __builtin_amdgcn_s_setprio(0);
        // ---- cluster C: overwrite a with m-half1 (WAR dep orders vs B); a * b1 ----
#pragma unroll
        for (int mf = 0; mf < 4; mf++) {
            int row = wr * 128 + 64 + mf * 16 + lr;
            int sw = (row & 7) << 4;
            a[mf][0] = *(const bf16x8*)(pA + row * 128 + ((lg * 16) ^ sw));
            a[mf][1] = *(const bf16x8*)(pA + row * 128 + ((64 + lg * 16) ^ sw));
        }
        __builtin_amdgcn_s_setprio(1);
#pragma unroll
        for (int mf = 0; mf < 4; mf++)
#pragma unroll
            for (int nf = 0; nf < 2; nf++) {
                acc[4 + mf][nf + 2] = __builtin_amdgcn_mfma_f32_16x16x32_bf16(a[mf][0], b1[nf][0], acc[4 + mf][nf + 2], 0, 0, 0);
                acc[4 + mf][nf + 2] = __builtin_amdgcn_mfma_f32_16x16x32_bf16(a[mf][1], b1[nf][1], acc[4 + mf][nf + 2], 0, 0, 0);
            }
        __builtin_amdgcn_s_setprio(0);
        // ---- bar1: every ds_read above was consumed by an MFMA -> lgkm drained;
        //      after this barrier no wave reads buf[cur] again ----
        __builtin_amdgcn_sched_barrier(0);
        __builtin_amdgcn_s_barrier();
        __builtin_amdgcn_sched_barrier(0);
        // ---- stage tile t+2 into the freed buffer (overlaps cluster D) ----
        if (t + 2 < nt) {
            const int k2 = (t + 2) * 64;
            STAGE(&As[cur][0], &Bs[cur][0],
                  (k2 >= 768) ? k2 - 768 : k2,
                  (k2 >= 1536) ? k2 - 1536 : k2);
        }
        __builtin_amdgcn_sched_barrier(0);   // keep D's MFMAs after the stage issue
        // ---- cluster D: a(m-half1) * b0 — registers only ----
        __builtin_amdgcn_s_setprio(1);
#pragma unroll
        for (int mf = 0; mf < 4; mf++)
#pragma unroll
            for (int nf = 0; nf < 2; nf++) {
                acc[4 + mf][nf] = __builtin_amdgcn_mfma_f32_16x16x32_bf16(a[mf][0], b0[nf][0], acc[4 + mf][nf], 0, 0, 0);
                acc[4 + mf][nf] = __builtin_amdgcn_mfma_f32_16x16x32_bf16(a[mf][1], b0[nf][1], acc[4 + mf][nf], 0, 0, 0);
            }
        __builtin_amdgcn_s_setprio(0);
        // ---- counted wait for tile t+1 (t+2's 8 loads stay in flight) ----
        if (t + 2 < nt) {
            asm volatile("s_waitcnt vmcnt(8)" ::: "memory");
        } else {
            asm volatile("s_waitcnt vmcnt(0)" ::: "memory");
        }
        __builtin_amdgcn_sched_barrier(0);
        __builtin_amdgcn_s_barrier();            // t+1's LDS writes visible to all
        __builtin_amdgcn_sched_barrier(0);
        cur ^= 1;
    }
    // ---- epilogue: bias (+ LoRA), store ----
#pragma unroll
    for (int mf = 0; mf < 8; mf++) {
#pragma unroll
        for (int r = 0; r < 4; r++) {
            int m = m0 + wr * 128 + mf * 16 + lg * 4 + r;
            if (m < M) {
                float mr[8];
                if constexpr (LORA) {
                    float4 u0 = *reinterpret_cast<const float4*>(mid + (size_t)m * 8);
                    float4 u1 = *reinterpret_cast<const float4*>(mid + (size_t)m * 8 + 4);
                    mr[0] = u0.x; mr[1] = u0.y; mr[2] = u0.z; mr[3] = u0.w;
                    mr[4] = u1.x; mr[5] = u1.y; mr[6] = u1.z; mr[7] = u1.w;
                }
#pragma unroll
                for (int nf = 0; nf < 4; nf++) {
                    int n = n0 + wc * 64 + nf * 16 + lr;
                    float v = acc[mf][nf][r] + bias[n];
                    if constexpr (LORA) {
                        const float4 l0 = *reinterpret_cast<const float4*>(lb + (size_t)n * 8);
                        const float4 l1 = *reinterpret_cast<const float4*>(lb + (size_t)n * 8 + 4);
                        v += mr[0] * l0.x + mr[1] * l0.y + mr[2] * l0.z + mr[3] * l0.w
                           + mr[4] * l1.x + mr[5] * l1.y + mr[6] * l1.z + mr[7] * l1.w;
                    }
                    storeC(C + (size_t)m * N + n, v);
                }
            }
        }
    }
}

// ---------------- Fused per-frame attention, MFMA version ----------------
__global__ __launch_bounds__(256) void attn_kernel(const bf16* __restrict__ qkv,
        bf16* __restrict__ ao) {
    __shared__ bf16 Ks[208 * 64];      // [row][64]
    __shared__ bf16 Vt[64 * 208];      // [d][kk]
    __shared__ bf16 Ps[4][16 * 208];   // per-wave [q][kk]
    const int bb = blockIdx.x / NH;
    const int h = blockIdx.x % NH;
    const bf16* base = qkv + (size_t)bb * TP * N3;
    const int tid = threadIdx.x;
    const int w = tid >> 6, lane = tid & 63;
    const int lr = lane & 15, lg = lane >> 4;

    for (int idx = tid; idx < 208 * 16; idx += 256) {
        int row = idx >> 4, d4 = (idx & 15) * 4;
        ushort4 v = make_ushort4(0, 0, 0, 0);
        if (row < TP)
            v = *(const ushort4*)(base + (size_t)row * N3 + EDIM + h * 64 + d4);
        *(ushort4*)((char*)Ks + ((row * 128 + d4 * 2) ^ ((row & 7) << 4))) = v;
    }
    for (int g = w; g < 52; g += 4) {
        int kk0 = g * 4;
        int d = lane;
        const bf16* vb = base + (size_t)kk0 * N3 + 2 * EDIM + h * 64 + d;
        unsigned short t0 = 0, t1 = 0, t2 = 0, t3 = 0;
        if (kk0 + 0 < TP) t0 = *(const unsigned short*)(vb);
        if (kk0 + 1 < TP) t1 = *(const unsigned short*)(vb + N3);
        if (kk0 + 2 < TP) t2 = *(const unsigned short*)(vb + 2 * N3);
        if (kk0 + 3 < TP) t3 = *(const unsigned short*)(vb + 3 * N3);
        ushort4 v; v.x = t0; v.y = t1; v.z = t2; v.w = t3;
        *(ushort4*)((char*)Vt + ((d * 416 + kk0 * 2) ^ ((d & 7) << 4))) = v;
    }
    __syncthreads();

    bf16* Pw = &Ps[w][0];

    for (int qt = w; qt < 13; qt += 4) {
        int q = qt * 16 + lr; if (q > TP - 1) q = TP - 1;
        const bf16* qp = base + (size_t)q * N3 + h * 64 + lg * 8;
        bf16x8 qa0 = *(const bf16x8*)qp;
        bf16x8 qa1 = *(const bf16x8*)(qp + 32);

        f32x4 sf[13];
#pragma unroll
        for (int f = 0; f < 13; f++) {
            int row = f * 16 + lr;
            int swz = (row & 7) << 4;
            bf16x8 kb0 = *(const bf16x8*)((const char*)Ks + ((row * 128 + lg * 16) ^ swz));
            bf16x8 kb1 = *(const bf16x8*)((const char*)Ks + ((row * 128 + 64 + lg * 16) ^ swz));
            f32x4 c = {0.f, 0.f, 0.f, 0.f};
            c = __builtin_amdgcn_mfma_f32_16x16x32_bf16(qa0, kb0, c, 0, 0, 0);
            c = __builtin_amdgcn_mfma_f32_16x16x32_bf16(qa1, kb1, c, 0, 0, 0);
            sf[f] = c;
        }

        float mx[4] = {-1e30f, -1e30f, -1e30f, -1e30f};
#pragma unroll
        for (int f = 0; f < 13; f++) {
#pragma unroll
            for (int r = 0; r < 4; r++) {
                float s = sf[f][r] * SCALE;
                if (f == 12 && lr >= 5) s = -1e30f;
                sf[f][r] = s;
                mx[r] = fmaxf(mx[r], s);
            }
        }
#pragma unroll
        for (int off = 8; off >= 1; off >>= 1) {
#pragma unroll
            for (int r = 0; r < 4; r++) mx[r] = fmaxf(mx[r], __shfl_xor(mx[r], off, 64));
        }
        float lsum[4] = {0.f, 0.f, 0.f, 0.f};
#pragma unroll
        for (int f = 0; f < 13; f++) {
#pragma unroll
            for (int r = 0; r < 4; r++) {
                float e = __expf(sf[f][r] - mx[r]);
                sf[f][r] = e;
                lsum[r] += e;
            }
        }
#pragma unroll
        for (int off = 8; off >= 1; off >>= 1) {
#pragma unroll
            for (int r = 0; r < 4; r++) lsum[r] += __shfl_xor(lsum[r], off, 64);
        }
        float inv[4];
#pragma unroll
        for (int r = 0; r < 4; r++) inv[r] = 1.f / lsum[r];

#pragma unroll
        for (int f = 0; f < 13; f++) {
#pragma unroll
            for (int r = 0; r < 4; r++) {
                int row = lg * 4 + r;
                int col = f * 16 + lr;
                *(bf16*)((char*)Pw + ((row * 416 + col * 2) ^ ((row & 7) << 4))) =
                    __float2bfloat16(sf[f][r]);
            }
        }

        f32x4 of[4];
#pragma unroll
        for (int dt = 0; dt < 4; dt++) of[dt] = (f32x4){0.f, 0.f, 0.f, 0.f};
#pragma unroll
        for (int ks = 0; ks < 7; ks++) {
            int k0 = ks * 32 + lg * 8;
            bool ok = (k0 < 208);
            bf16x8 pa = {0, 0, 0, 0, 0, 0, 0, 0};
            if (ok)
                pa = *(const bf16x8*)((const char*)Pw + ((lr * 416 + k0 * 2) ^ ((lr & 7) << 4)));
#pragma unroll
            for (int dt = 0; dt < 4; dt++) {
                bf16x8 vb = {0, 0, 0, 0, 0, 0, 0, 0};
                if (ok) {
                    int d = dt * 16 + lr;
                    vb = *(const bf16x8*)((const char*)Vt + ((d * 416 + k0 * 2) ^ ((d & 7) << 4)));
                }
                of[dt] = __builtin_amdgcn_mfma_f32_16x16x32_bf16(pa, vb, of[dt], 0, 0, 0);
            }
        }

#pragma unroll
        for (int dt = 0; dt < 4; dt++) {
#pragma unroll
            for (int r = 0; r < 4; r++) {
                int qq = qt * 16 + lg * 4 + r;
                if (qq < TP)
                    ao[((size_t)bb * TP + qq) * EDIM + h * 64 + dt * 16 + lr] =
                        __float2bfloat16(of[dt][r] * inv[r]);
            }
        }
    }
}

// ---------------- Fused cross-frame CLS attention (flash-style online softmax) ----------
__global__ __launch_bounds__(256) void xattn_kernel(const bf16* __restrict__ qkv,
        float* __restrict__ x1p) {
    __shared__ float q1[NF][64];
    __shared__ bf16 Ks[128][64];
    __shared__ bf16 Vs[128][64];
    __shared__ float sc[NF][128];
    __shared__ float Oacc[NF][64];
    __shared__ float mrow[NF], lrow[NF], arow[NF];
    const int b = blockIdx.x / NH, h = blockIdx.x % NH;
    const int tid = threadIdx.x;
    for (int idx = tid; idx < NF * 64; idx += 256) {
        int f = idx >> 6, d = idx & 63;
        q1[f][d] = b2f(qkv[(size_t)((b * NF + f) * TP) * N3 + h * 64 + d]);
        Oacc[f][d] = 0.f;
    }
    if (tid < NF) { mrow[tid] = -1e30f; lrow[tid] = 0.f; }
    __syncthreads();
    const int w = tid >> 6, lane = tid & 63;
    for (int kk0 = 0; kk0 < KALL; kk0 += 128) {
        for (int idx = tid; idx < 128 * 16; idx += 256) {
            int r = idx >> 4, d4 = (idx & 15) * 4;
            int kk = kk0 + r;
            if (kk < KALL) {
                int f = kk / TP, pp = kk - f * TP;
                const bf16* src = qkv + (size_t)((b * NF + f) * TP + pp) * N3 + h * 64 + d4;
                *(ushort4*)&Ks[r][d4] = *(const ushort4*)(src + 768);
                *(ushort4*)&Vs[r][d4] = *(const ushort4*)(src + 1536);
            } else {
                ushort4 z; z.x = z.y = z.z = z.w = 0;
                *(ushort4*)&Ks[r][d4] = z;
                *(ushort4*)&Vs[r][d4] = z;
            }
        }
        __syncthreads();
        for (int idx = tid; idx < NF * 128; idx += 256) {
            int f = idx >> 7, r = idx & 127;
            float s = -1e30f;
            if (kk0 + r < KALL) {
                const bf16* kr = &Ks[r][0];
                float a = 0.f;
#pragma unroll
                for (int d2 = 0; d2 < 32; d2++) {
                    unsigned int u = *reinterpret_cast<const unsigned int*>(kr + 2 * d2);
                    a += q1[f][2 * d2] * __uint_as_float(u << 16);
                    a += q1[f][2 * d2 + 1] * __uint_as_float(u & 0xffff0000u);
                }
                s = a * SCALE;
            }
            sc[f][r] = s;
        }
        __syncthreads();
        for (int qi = 0; qi < 3; qi++) {
            int f = qi * 4 + w;
            float s0 = sc[f][lane], s1v = sc[f][lane + 64];
            float mx = fmaxf(s0, s1v);
#pragma unroll
            for (int off = 32; off >= 1; off >>= 1) mx = fmaxf(mx, __shfl_xor(mx, off, 64));
            float mold = mrow[f];
            float mnew = fmaxf(mold, mx);
            float e0 = __expf(s0 - mnew), e1 = __expf(s1v - mnew);
            float ls = e0 + e1;
#pragma unroll
            for (int off = 32; off >= 1; off >>= 1) ls += __shfl_xor(ls, off, 64);
            sc[f][lane] = e0; sc[f][lane + 64] = e1;
            if (lane == 0) {
                float alpha = __expf(mold - mnew);
                arow[f] = alpha;
                lrow[f] = lrow[f] * alpha + ls;
                mrow[f] = mnew;
            }
        }
        __syncthreads();
        for (int idx = tid; idx < NF * 64; idx += 256) {
            int f = idx >> 6, d = idx & 63;
            float o = Oacc[f][d] * arow[f];
#pragma unroll 4
            for (int r = 0; r < 128; r++)
                o += sc[f][r] * b2f(Vs[r][d]);
            Oacc[f][d] = o;
        }
        __syncthreads();
    }
    for (int idx = tid; idx < NF * 64; idx += 256) {
        int f = idx >> 6, d = idx & 63;
        x1p[(size_t)(b * NF + f) * EDIM + h * 64 + d] = Oacc[f][d] / lrow[f];
    }
}

// ---------------- CLS fixup: out[:,:,0,:] = MLP(out[:,:,0,:]) + x1p @ Wout^T + ob --------
__global__ __launch_bounds__(256) void cls_kernel(float* __restrict__ out,
        const float* __restrict__ x1p, const float* __restrict__ Wout, const float* __restrict__ ob,
        const float* __restrict__ dw, const float* __restrict__ db,
        const float* __restrict__ uw, const float* __restrict__ ub) {
    __shared__ float x0s[EDIM], x1s[EDIM], gs[8];
    const int bfi = blockIdx.x;
    float* row = out + (size_t)bfi * TP * EDIM;  // p = 0 row
    const int tid = threadIdx.x;
    for (int i = tid; i < EDIM; i += 256) {
        x0s[i] = row[i];
        x1s[i] = x1p[(size_t)bfi * EDIM + i];
    }
    __syncthreads();
    {
        int r = tid >> 5, sl = tid & 31;
        float pr = 0.f;
        for (int e = sl; e < EDIM; e += 32) pr += x0s[e] * dw[r * EDIM + e];
#pragma unroll
        for (int off = 16; off >= 1; off >>= 1) pr += __shfl_xor(pr, off, 64);
        if (sl == 0) gs[r] = pr + db[r];
    }
    __syncthreads();
    float act[8];
#pragma unroll
    for (int r = 0; r < 8; r++) { float g = gs[r]; act[r] = g / (1.f + __expf(-1.702f * g)); }
    for (int j = tid; j < EDIM; j += 256) {
        float y = ub[j] + ob[j];
        const float4 u0 = *reinterpret_cast<const float4*>(uw + (size_t)j * 8);
        const float4 u1 = *reinterpret_cast<const float4*>(uw + (size_t)j * 8 + 4);
        y += act[0] * u0.x + act[1] * u0.y + act[2] * u0.z + act[3] * u0.w
           + act[4] * u1.x + act[5] * u1.y + act[6] * u1.z + act[7] * u1.w;
        const float* wr = Wout + (size_t)j * EDIM;
        float s = 0.f;
        for (int e = 0; e < EDIM; e += 4) {
            float4 wv = *reinterpret_cast<const float4*>(wr + e);
            s += x1s[e] * wv.x + x1s[e + 1] * wv.y + x1s[e + 2] * wv.z + x1s[e + 3] * wv.w;
        }
        y += s;
        row[j] = y;
    }
}

extern "C" void kernel_launch(void* const* d_in, const int* in_sizes, int n_in,
                              void* d_out, int out_size, void* d_ws, size_t ws_size,
                              hipStream_t stream) {
    (void)in_sizes; (void)n_in; (void)out_size; (void)ws_size;
    const float* x   = (const float*)d_in[0];
    const float* ipw = (const float*)d_in[1];
    const float* ipb = (const float*)d_in[2];
    const float* opw = (const float*)d_in[3];
    const float* opb = (const float*)d_in[4];
    const float* la  = (const float*)d_in[5];
    const float* lb  = (const float*)d_in[6];
    const float* dw  = (const float*)d_in[7];
    const float* db  = (const float*)d_in[8];
    const float* uw  = (const float*)d_in[9];
    const float* ub  = (const float*)d_in[10];
    float* out = (float*)d_out;   // fp32 output per reference dtype

    // workspace: qkv 174.3 + ao 58.2 + xs 116.4 + W1 7.1 + W2 2.4 + mid 1.2 + x1p 0.6 ≈ 360 MB
    char* wsb = (char*)d_ws;
    bf16* qkv = (bf16*)wsb;                       wsb += (size_t)NT * N3 * sizeof(bf16);
    bf16* ao  = (bf16*)wsb;                       wsb += (size_t)MPAD * EDIM * sizeof(bf16);
    bf16* xs  = (bf16*)wsb;                       wsb += (size_t)MPAD * 1536 * sizeof(bf16);
    bf16* W1  = (bf16*)wsb;                       wsb += (size_t)N3 * 1536 * sizeof(bf16);
    bf16* W2  = (bf16*)wsb;                       wsb += (size_t)EDIM * 1536 * sizeof(bf16);
    float* mid = (float*)wsb;                     wsb += (size_t)NT * 8 * sizeof(float);
    float* x1p = (float*)wsb;                     wsb += (size_t)NB * NF * EDIM * sizeof(float);

    split_w_kernel<<<(N3 * 192 + 255) / 256, 256, 0, stream>>>(ipw, W1, N3);
    split_w_kernel<<<(EDIM * 192 + 255) / 256, 256, 0, stream>>>(opw, W2, EDIM);
    split_w_kernel<<<(NT * 192 + 255) / 256, 256, 0, stream>>>(x, xs, NT);
    lora_mid_kernel<<<NT / 4, 256, 0, stream>>>(x, la, mid);
    // QKV: virtual K = 2304 (hi*Whi + hi*Wlo + lo*Whi)
    mfma_gemm_kernel<bf16, true><<<dim3(N3 / 256, MPAD / 256), 512, 0, stream>>>(
        xs, 1536, W1, ipb, mid, lb, qkv, NT, N3, 2304);
    attn_kernel<<<192 * NH, 256, 0, stream>>>(qkv, ao);
    xattn_kernel<<<NB * NH, 256, 0, stream>>>(qkv, x1p);
    // out-proj: virtual K = 1536 (ao*Whi + ao*Wlo)
    mfma_gemm_kernel<float, false><<<dim3(EDIM / 256, MPAD / 256), 512, 0, stream>>>(
        ao, 768, W2, opb, nullptr, nullptr, out, NT, EDIM, 1536);
    cls_kernel<<<NB * NF, 256, 0, stream>>>(out, x1p, opw, opb, dw, db, uw, ub);
}